// Round 6
// baseline (390.431 us; speedup 1.0000x reference)
//
#include <hip/hip_runtime.h>

#define FD 128
#define NH 4
#define HF 512

typedef __attribute__((ext_vector_type(8))) short short8;
typedef __attribute__((ext_vector_type(4))) float v4f;

__device__ __forceinline__ float lrelu(float x, float s) { return x > 0.f ? x : s * x; }

__device__ __forceinline__ unsigned short f2bf(float f) {
    unsigned int u = __float_as_uint(f);
    u += 0x7FFFu + ((u >> 16) & 1u);          // RNE
    return (unsigned short)(u >> 16);
}
__device__ __forceinline__ unsigned int pack2(float a, float b) {
    return (unsigned)f2bf(a) | ((unsigned)f2bf(b) << 16);
}

// ---------------- fused prep: cast x->bf16, weight transpose-casts, u=Wg_h@att, degree count
__global__ __launch_bounds__(256) void k_prep(const float* __restrict__ x,
                                              unsigned short* __restrict__ xb,
                                              const float* __restrict__ Wg, unsigned short* __restrict__ WgT,
                                              const float* __restrict__ Wm, unsigned short* __restrict__ WmT,
                                              const float* __restrict__ W1, unsigned short* __restrict__ W1T,
                                              const float* __restrict__ W2, unsigned short* __restrict__ W2T,
                                              const float* __restrict__ att_s,
                                              const float* __restrict__ att_d,
                                              float* __restrict__ U,
                                              const int* __restrict__ dst, int* __restrict__ cnt,
                                              int n, int E) {
    const int t = threadIdx.x;
    int b = blockIdx.x;
    const int nCast = (n * FD / 8 + 255) / 256;
    const int nT1 = (FD * HF / 4 + 255) / 256;
    const int nT3 = (FD * FD / 4 + 255) / 256;
    const int nU = 4;
    if (b < nCast) {
        int i = b * 256 + t;
        if (i < n * FD / 8) {
            const float4* x4 = reinterpret_cast<const float4*>(x);
            float4 v0 = x4[i * 2], v1 = x4[i * 2 + 1];
            uint4 o;
            o.x = pack2(v0.x, v0.y); o.y = pack2(v0.z, v0.w);
            o.z = pack2(v1.x, v1.y); o.w = pack2(v1.z, v1.w);
            reinterpret_cast<uint4*>(xb)[i] = o;
        }
        return;
    }
    b -= nCast;
    if (b < nT1) {   // WgT[512][128] <- Wg[128][512]
        int i4 = (b * 256 + t) * 4;
        if (i4 < FD * HF) {
            int nn = i4 >> 7, k = i4 & 127;
            uint2 o;
            o.x = pack2(Wg[(size_t)k * HF + nn], Wg[(size_t)(k + 1) * HF + nn]);
            o.y = pack2(Wg[(size_t)(k + 2) * HF + nn], Wg[(size_t)(k + 3) * HF + nn]);
            *reinterpret_cast<uint2*>(&WgT[i4]) = o;
        }
        return;
    }
    b -= nT1;
    if (b < nT1) {   // WmT[128][512] <- Wm[512][128]
        int i4 = (b * 256 + t) * 4;
        if (i4 < HF * FD) {
            int nn = i4 >> 9, k = i4 & 511;
            uint2 o;
            o.x = pack2(Wm[(size_t)k * FD + nn], Wm[(size_t)(k + 1) * FD + nn]);
            o.y = pack2(Wm[(size_t)(k + 2) * FD + nn], Wm[(size_t)(k + 3) * FD + nn]);
            *reinterpret_cast<uint2*>(&WmT[i4]) = o;
        }
        return;
    }
    b -= nT1;
    if (b < nT3) {   // W1T[128][128]
        int i4 = (b * 256 + t) * 4;
        if (i4 < FD * FD) {
            int nn = i4 >> 7, k = i4 & 127;
            uint2 o;
            o.x = pack2(W1[(size_t)k * FD + nn], W1[(size_t)(k + 1) * FD + nn]);
            o.y = pack2(W1[(size_t)(k + 2) * FD + nn], W1[(size_t)(k + 3) * FD + nn]);
            *reinterpret_cast<uint2*>(&W1T[i4]) = o;
        }
        return;
    }
    b -= nT3;
    if (b < nT3) {   // W2T[128][128]
        int i4 = (b * 256 + t) * 4;
        if (i4 < FD * FD) {
            int nn = i4 >> 7, k = i4 & 127;
            uint2 o;
            o.x = pack2(W2[(size_t)k * FD + nn], W2[(size_t)(k + 1) * FD + nn]);
            o.y = pack2(W2[(size_t)(k + 2) * FD + nn], W2[(size_t)(k + 3) * FD + nn]);
            *reinterpret_cast<uint2*>(&W2T[i4]) = o;
        }
        return;
    }
    b -= nT3;
    if (b < nU) {    // U[0..511]=u_s[h][k], U[512..1023]=u_d[h][k]
        int idx = b * 256 + t;
        int type = idx >> 9, h = (idx >> 7) & 3, k = idx & 127;
        const float* att = type ? att_d : att_s;
        const float* wrow = &Wg[(size_t)k * HF + h * FD];
        const float* arow = &att[h * FD];
        float s = 0.f;
#pragma unroll 4
        for (int j = 0; j < FD; ++j) s += wrow[j] * arow[j];
        U[idx] = s;
        return;
    }
    b -= nU;
    {
        int i = b * 256 + t;
        if (i < E) atomicAdd(&cnt[dst[i]], 1);
    }
}

// ---------------- a_s[n,h] = x[n]·u_s[h], a_d[n,h] = x[n]·u_d[h]   (fp32)
__global__ __launch_bounds__(256) void k_alog(const float* __restrict__ x,
                                              const float* __restrict__ U,
                                              float* __restrict__ a_s,
                                              float* __restrict__ a_d, int n) {
    int idx = blockIdx.x * 256 + threadIdx.x;
    int node = idx >> 2, h = idx & 3;
    if (node >= n) return;
    const float4* xr = reinterpret_cast<const float4*>(&x[(size_t)node * FD]);
    const float4* us = reinterpret_cast<const float4*>(&U[h * FD]);
    const float4* ud = reinterpret_cast<const float4*>(&U[512 + h * FD]);
    float ps = 0.f, pd = 0.f;
#pragma unroll 8
    for (int j = 0; j < 32; ++j) {
        float4 v = xr[j], a = us[j], bb = ud[j];
        ps += v.x * a.x + v.y * a.y + v.z * a.z + v.w * a.w;
        pd += v.x * bb.x + v.y * bb.y + v.z * bb.z + v.w * bb.w;
    }
    a_s[node * NH + h] = ps;
    a_d[node * NH + h] = pd;
}

// ---------------- multi-block exclusive scan (3 phases)
__global__ __launch_bounds__(1024) void k_scanA(const int* __restrict__ cnt,
                                                int* __restrict__ bsum, int n) {
    __shared__ int wtot[16];
    const int b = blockIdx.x, t = threadIdx.x;
    const int lane = t & 63, wid = t >> 6;
    const int idx = b * 4096 + t * 4;
    int s = 0;
    if (idx + 3 < n) {
        int4 v = *reinterpret_cast<const int4*>(&cnt[idx]);
        s = v.x + v.y + v.z + v.w;
    } else {
        for (int j = 0; j < 4; ++j) if (idx + j < n) s += cnt[idx + j];
    }
#pragma unroll
    for (int d = 1; d < 64; d <<= 1) s += __shfl_xor(s, d);
    if (lane == 0) wtot[wid] = s;
    __syncthreads();
    if (t == 0) {
        int tot = 0;
#pragma unroll
        for (int i = 0; i < 16; ++i) tot += wtot[i];
        bsum[b] = tot;
    }
}

__global__ void k_scanB(const int* __restrict__ bsum, int* __restrict__ bpre, int nb) {
    const int l = threadIdx.x;
    int v = (l < nb) ? bsum[l] : 0;
    int incl = v;
#pragma unroll
    for (int d = 1; d < 64; d <<= 1) {
        int o = __shfl_up(incl, d);
        if (l >= d) incl += o;
    }
    if (l < nb) bpre[l] = incl - v;
}

__global__ __launch_bounds__(1024) void k_scanC(const int* __restrict__ cnt,
                                                const int* __restrict__ bpre,
                                                int* __restrict__ off,
                                                int* __restrict__ cur, int n) {
    __shared__ int wtot[16];
    const int b = blockIdx.x, t = threadIdx.x;
    const int lane = t & 63, wid = t >> 6;
    const int idx = b * 4096 + t * 4;
    int4 v = make_int4(0, 0, 0, 0);
    if (idx + 3 < n) v = *reinterpret_cast<const int4*>(&cnt[idx]);
    else {
        if (idx < n) v.x = cnt[idx];
        if (idx + 1 < n) v.y = cnt[idx + 1];
        if (idx + 2 < n) v.z = cnt[idx + 2];
        if (idx + 3 < n) v.w = cnt[idx + 3];
    }
    const int p1 = v.x, p2 = p1 + v.y, p3 = p2 + v.z, ts = p3 + v.w;
    int incl = ts;
#pragma unroll
    for (int d = 1; d < 64; d <<= 1) {
        int o = __shfl_up(incl, d);
        if (lane >= d) incl += o;
    }
    if (lane == 63) wtot[wid] = incl;
    __syncthreads();
    int wbase = 0;
#pragma unroll
    for (int i = 0; i < 16; ++i) if (i < wid) wbase += wtot[i];
    const int base = bpre[b] + wbase + (incl - ts);
    if (idx < n)     { cur[idx] = base;          off[idx + 1] = base + p1; }
    if (idx + 1 < n) { cur[idx + 1] = base + p1; off[idx + 2] = base + p2; }
    if (idx + 2 < n) { cur[idx + 2] = base + p2; off[idx + 3] = base + p3; }
    if (idx + 3 < n) { cur[idx + 3] = base + p3; off[idx + 4] = base + ts; }
    if (b == 0 && t == 0) off[0] = 0;
}

// ---------------- scatter edges into CSR slots, with leaky(0.2) logits
__global__ __launch_bounds__(256) void k_scatter(const int* __restrict__ es,
                                                 const int* __restrict__ ed,
                                                 const float* __restrict__ a_s,
                                                 const float* __restrict__ a_d,
                                                 int* __restrict__ cur,
                                                 int* __restrict__ ssort,
                                                 float4* __restrict__ asort, int e) {
    int i = blockIdx.x * 256 + threadIdx.x;
    if (i >= e) return;
    int s = es[i], d = ed[i];
    const float4 as = *reinterpret_cast<const float4*>(&a_s[(size_t)s * NH]);
    const float4 ad = *reinterpret_cast<const float4*>(&a_d[(size_t)d * NH]);
    float4 al;
    al.x = lrelu(as.x + ad.x, 0.2f);
    al.y = lrelu(as.y + ad.y, 0.2f);
    al.z = lrelu(as.z + ad.z, 0.2f);
    al.w = lrelu(as.w + ad.w, 0.2f);
    int pos = atomicAdd(&cur[d], 1);
    ssort[pos] = s;
    asort[pos] = al;
}

// ---------------- per-node (one wave) aggregation in x-space -> agg bf16 [n][h*128+k]
__global__ __launch_bounds__(256) void k_aggr2(const unsigned short* __restrict__ xb,
                                               const float* __restrict__ a_s,
                                               const float* __restrict__ a_d,
                                               const int* __restrict__ off,
                                               const int* __restrict__ ssort,
                                               const float* __restrict__ asort,
                                               unsigned short* __restrict__ agg, int n) {
    const int w = threadIdx.x >> 6, l = threadIdx.x & 63;
    const int node = blockIdx.x * 4 + w;
    if (node >= n) return;
    const int e16 = l & 15;
    const int o0 = off[node], deg = off[node + 1] - o0;

    float wS[4];
#pragma unroll
    for (int hh = 0; hh < 4; ++hh)
        wS[hh] = __expf(lrelu(a_s[node * NH + hh] + a_d[node * NH + hh], 0.2f));

    float acc[8];   // [h][2 feats]
    {
        unsigned int ux = *reinterpret_cast<const unsigned int*>(&xb[(size_t)node * FD + 2 * l]);
        float f0 = __uint_as_float(ux << 16);
        float f1 = __uint_as_float(ux & 0xffff0000u);
#pragma unroll
        for (int hh = 0; hh < 4; ++hh) { acc[hh * 2] = f0 * wS[hh]; acc[hh * 2 + 1] = f1 * wS[hh]; }
    }
    const int* sso = ssort + o0;
    const float* aso = asort + (size_t)o0 * 4 + (l >> 4);
    float sswl = 0.f;

    int base = 0;
    int sidx = 0; float wl = 0.f;
    if (16 <= deg) { sidx = sso[e16]; wl = __expf(aso[4 * e16]); }
    while (base + 16 <= deg) {
        const int nb2 = base + 16;
        int sN = 0; float wN = 0.f;
        if (nb2 + 16 <= deg) { sN = sso[nb2 + e16]; wN = __expf(aso[4 * (nb2 + e16)]); }
        sswl += wl;
#pragma unroll
        for (int e = 0; e < 16; ++e) {
            int s = __shfl(sidx, e);
            float w0 = __shfl(wl, e);
            float w1 = __shfl(wl, 16 + e);
            float w2 = __shfl(wl, 32 + e);
            float w3 = __shfl(wl, 48 + e);
            unsigned int u = *reinterpret_cast<const unsigned int*>(&xb[(size_t)s * FD + 2 * l]);
            float f0 = __uint_as_float(u << 16);
            float f1 = __uint_as_float(u & 0xffff0000u);
            acc[0] += f0 * w0; acc[1] += f1 * w0;
            acc[2] += f0 * w1; acc[3] += f1 * w1;
            acc[4] += f0 * w2; acc[5] += f1 * w2;
            acc[6] += f0 * w3; acc[7] += f1 * w3;
        }
        sidx = sN; wl = wN; base = nb2;
    }
    const int rem = deg - base;
    if (rem > 0) {
        int s2 = 0; float w2l = 0.f;
        if (e16 < rem) { s2 = sso[base + e16]; w2l = __expf(aso[4 * (base + e16)]); }
        sswl += w2l;
        for (int e = 0; e < rem; ++e) {
            int s = __shfl(s2, e);
            float w0 = __shfl(w2l, e);
            float w1 = __shfl(w2l, 16 + e);
            float w2 = __shfl(w2l, 32 + e);
            float w3 = __shfl(w2l, 48 + e);
            unsigned int u = *reinterpret_cast<const unsigned int*>(&xb[(size_t)s * FD + 2 * l]);
            float f0 = __uint_as_float(u << 16);
            float f1 = __uint_as_float(u & 0xffff0000u);
            acc[0] += f0 * w0; acc[1] += f1 * w0;
            acc[2] += f0 * w1; acc[3] += f1 * w1;
            acc[4] += f0 * w2; acc[5] += f1 * w2;
            acc[6] += f0 * w3; acc[7] += f1 * w3;
        }
    }
#pragma unroll
    for (int d = 1; d < 16; d <<= 1) sswl += __shfl_xor(sswl, d);
    float inv[4];
#pragma unroll
    for (int hh = 0; hh < 4; ++hh) inv[hh] = 1.f / (__shfl(sswl, hh * 16) + wS[hh]);
#pragma unroll
    for (int hh = 0; hh < 4; ++hh) {
        unsigned int o = pack2(acc[hh * 2] * inv[hh], acc[hh * 2 + 1] * inv[hh]);
        *reinterpret_cast<unsigned int*>(&agg[(size_t)node * HF + hh * FD + 2 * l]) = o;
    }
}

// ---------------- fused tail: hm = sum_h lrelu(agg_h@Wg_h+bg_h)@Wm_h + bm + x;
// out = lrelu(hm@W1+b1)@W2 + b2 + hm.  One 17KB LDS buffer bridges all stages.
__global__ __launch_bounds__(256, 4) void k_tail(const unsigned short* __restrict__ agg,
                                                 const unsigned short* __restrict__ WgT,
                                                 const float* __restrict__ biasg,
                                                 const unsigned short* __restrict__ WmT,
                                                 const float* __restrict__ bm,
                                                 const float* __restrict__ x,
                                                 const unsigned short* __restrict__ W1T,
                                                 const float* __restrict__ b1,
                                                 const unsigned short* __restrict__ W2T,
                                                 const float* __restrict__ b2,
                                                 float* __restrict__ out, int n) {
    __shared__ unsigned short tS[64][136];
    const int m0 = blockIdx.x * 64;
    const int wv = threadIdx.x >> 6, l = threadIdx.x & 63;
    const int rA = l & 15;
    const int kg = (l >> 4) * 8;
    const int mw = m0 + wv * 16;
    const int amr = min(mw + rA, n - 1);
    const int lr0 = wv * 16 + (l >> 4) * 4;

    v4f hma[8];
#pragma unroll
    for (int t = 0; t < 8; ++t) hma[t] = (v4f){0.f, 0.f, 0.f, 0.f};

    // ---- per-head: t_h = lrelu(agg_h @ Wg_h + bg_h); hm += t_h @ Wm_h
#pragma unroll 1
    for (int h = 0; h < 4; ++h) {
        v4f acc[8];
#pragma unroll
        for (int t = 0; t < 8; ++t) acc[t] = (v4f){0.f, 0.f, 0.f, 0.f};
#pragma unroll
        for (int kk = 0; kk < 4; ++kk) {
            short8 a = *reinterpret_cast<const short8*>(
                &agg[(size_t)amr * HF + h * FD + kk * 32 + kg]);
#pragma unroll
            for (int nt = 0; nt < 8; ++nt) {
                short8 b = *reinterpret_cast<const short8*>(
                    &WgT[(size_t)(h * FD + nt * 16 + rA) * FD + kk * 32 + kg]);
                acc[nt] = __builtin_amdgcn_mfma_f32_16x16x32_bf16(a, b, acc[nt], 0, 0, 0);
            }
        }
#pragma unroll
        for (int nt = 0; nt < 8; ++nt) {
            const int col = nt * 16 + rA;
            const float bv = biasg[h * FD + col];
#pragma unroll
            for (int i = 0; i < 4; ++i)
                tS[lr0 + i][col] = f2bf(lrelu(acc[nt][i] + bv, 0.01f));
        }
        __syncthreads();
#pragma unroll
        for (int kk = 0; kk < 4; ++kk) {
            short8 a = *reinterpret_cast<const short8*>(&tS[wv * 16 + rA][kk * 32 + kg]);
#pragma unroll
            for (int nt = 0; nt < 8; ++nt) {
                short8 b = *reinterpret_cast<const short8*>(
                    &WmT[(size_t)(nt * 16 + rA) * HF + h * FD + kk * 32 + kg]);
                hma[nt] = __builtin_amdgcn_mfma_f32_16x16x32_bf16(a, b, hma[nt], 0, 0, 0);
            }
        }
        __syncthreads();
    }

    // ---- hm finalize: + bm + x (fp32 in regs for exact residual; bf16 to LDS)
    float hmr[8][4];
#pragma unroll
    for (int nt = 0; nt < 8; ++nt) {
        const int col = nt * 16 + rA;
        const float bv = bm[col];
#pragma unroll
        for (int i = 0; i < 4; ++i) {
            const int r = min(mw + (l >> 4) * 4 + i, n - 1);
            float v = hma[nt][i] + bv + x[(size_t)r * FD + col];
            hmr[nt][i] = v;
            tS[lr0 + i][col] = f2bf(v);
        }
    }
    __syncthreads();

    // ---- FFN1: t2 = lrelu(hm @ W1 + b1)  (A from LDS)
    v4f acc[8];
#pragma unroll
    for (int t = 0; t < 8; ++t) acc[t] = (v4f){0.f, 0.f, 0.f, 0.f};
#pragma unroll
    for (int kk = 0; kk < 4; ++kk) {
        short8 a = *reinterpret_cast<const short8*>(&tS[wv * 16 + rA][kk * 32 + kg]);
#pragma unroll
        for (int nt = 0; nt < 8; ++nt) {
            short8 b = *reinterpret_cast<const short8*>(
                &W1T[(size_t)(nt * 16 + rA) * FD + kk * 32 + kg]);
            acc[nt] = __builtin_amdgcn_mfma_f32_16x16x32_bf16(a, b, acc[nt], 0, 0, 0);
        }
    }
    __syncthreads();   // all reads of hm done before overwrite
#pragma unroll
    for (int nt = 0; nt < 8; ++nt) {
        const int col = nt * 16 + rA;
        const float bv = b1[col];
#pragma unroll
        for (int i = 0; i < 4; ++i)
            tS[lr0 + i][col] = f2bf(lrelu(acc[nt][i] + bv, 0.01f));
    }
    __syncthreads();

    // ---- FFN2: out = t2 @ W2 + b2 + hm
#pragma unroll
    for (int t = 0; t < 8; ++t) acc[t] = (v4f){0.f, 0.f, 0.f, 0.f};
#pragma unroll
    for (int kk = 0; kk < 4; ++kk) {
        short8 a = *reinterpret_cast<const short8*>(&tS[wv * 16 + rA][kk * 32 + kg]);
#pragma unroll
        for (int nt = 0; nt < 8; ++nt) {
            short8 b = *reinterpret_cast<const short8*>(
                &W2T[(size_t)(nt * 16 + rA) * FD + kk * 32 + kg]);
            acc[nt] = __builtin_amdgcn_mfma_f32_16x16x32_bf16(a, b, acc[nt], 0, 0, 0);
        }
    }
#pragma unroll
    for (int nt = 0; nt < 8; ++nt) {
        const int col = nt * 16 + rA;
        const float bv = b2[col];
#pragma unroll
        for (int i = 0; i < 4; ++i) {
            const int r = mw + (l >> 4) * 4 + i;
            if (r < n)
                out[(size_t)r * FD + col] = acc[nt][i] + bv + hmr[nt][i];
        }
    }
}

extern "C" void kernel_launch(void* const* d_in, const int* in_sizes, int n_in,
                              void* d_out, int out_size, void* d_ws, size_t ws_size,
                              hipStream_t stream) {
    const float* x     = (const float*)d_in[0];
    const int*   ei    = (const int*)d_in[1];
    const float* Wg    = (const float*)d_in[2];
    const float* att_s = (const float*)d_in[3];
    const float* att_d = (const float*)d_in[4];
    const float* biasg = (const float*)d_in[5];
    const float* Wm    = (const float*)d_in[6];
    const float* bm    = (const float*)d_in[7];
    const float* W1    = (const float*)d_in[8];
    const float* b1    = (const float*)d_in[9];
    const float* W2    = (const float*)d_in[10];
    const float* b2    = (const float*)d_in[11];
    float* out = (float*)d_out;

    const int n = in_sizes[0] / FD;
    const int E = in_sizes[1] / 2;
    const int* esrc = ei;
    const int* edst = ei + E;

    char* w = (char*)d_ws;
    size_t o = 0;
    auto alloc = [&](size_t b) { void* p = w + o; o = (o + b + 255) & ~(size_t)255; return p; };
    unsigned short* x_b  = (unsigned short*)alloc((size_t)n * FD * 2);
    unsigned short* WgT  = (unsigned short*)alloc((size_t)FD * HF * 2);
    unsigned short* WmT  = (unsigned short*)alloc((size_t)HF * FD * 2);
    unsigned short* W1T  = (unsigned short*)alloc((size_t)FD * FD * 2);
    unsigned short* W2T  = (unsigned short*)alloc((size_t)FD * FD * 2);
    float*          U    = (float*)alloc(1024 * 4);
    unsigned short* aggb = (unsigned short*)alloc((size_t)n * HF * 2);
    float* a_s   = (float*)alloc((size_t)n * NH * 4);
    float* a_d   = (float*)alloc((size_t)n * NH * 4);
    int*   cnt   = (int*)alloc((size_t)n * 4);
    int*   offs  = (int*)alloc((size_t)(n + 1) * 4);
    int*   cur   = (int*)alloc((size_t)n * 4);
    int*   ssort = (int*)alloc((size_t)E * 4);
    float* asort = (float*)alloc((size_t)E * 16);
    int*   bsum  = (int*)alloc(256 * 4);
    int*   bpre  = (int*)alloc(256 * 4);

    hipMemsetAsync(cnt, 0, (size_t)n * 4, stream);

    const int nCast = (n * FD / 8 + 255) / 256;
    const int nT1 = (FD * HF / 4 + 255) / 256;
    const int nT3 = (FD * FD / 4 + 255) / 256;
    const int nU = 4;
    const int nCnt = (E + 255) / 256;
    k_prep<<<nCast + 2 * nT1 + 2 * nT3 + nU + nCnt, 256, 0, stream>>>(
        x, x_b, Wg, WgT, Wm, WmT, W1, W1T, W2, W2T, att_s, att_d, U, edst, cnt, n, E);

    k_alog<<<(n * 4 + 255) / 256, 256, 0, stream>>>(x, U, a_s, a_d, n);

    const int SB = (n + 4095) / 4096;
    k_scanA<<<SB, 1024, 0, stream>>>(cnt, bsum, n);
    k_scanB<<<1, 64, 0, stream>>>(bsum, bpre, SB);
    k_scanC<<<SB, 1024, 0, stream>>>(cnt, bpre, offs, cur, n);
    k_scatter<<<(E + 255) / 256, 256, 0, stream>>>(esrc, edst, a_s, a_d, cur, ssort,
                                                   (float4*)asort, E);
    k_aggr2<<<(n + 3) / 4, 256, 0, stream>>>(x_b, a_s, a_d, offs, ssort, asort, aggb, n);

    const int mb = (n + 63) / 64;
    k_tail<<<mb, 256, 0, stream>>>(aggb, WgT, biasg, WmT, bm, x, W1T, b1, W2T, b2, out, n);
}

// Round 7
// 315.184 us; speedup vs baseline: 1.2387x; 1.2387x over previous
//
#include <hip/hip_runtime.h>

#define FD 128
#define NH 4
#define HF 512

typedef __attribute__((ext_vector_type(8))) short short8;
typedef __attribute__((ext_vector_type(4))) float v4f;

__device__ __forceinline__ float lrelu(float x, float s) { return x > 0.f ? x : s * x; }

__device__ __forceinline__ unsigned short f2bf(float f) {
    unsigned int u = __float_as_uint(f);
    u += 0x7FFFu + ((u >> 16) & 1u);          // RNE
    return (unsigned short)(u >> 16);
}
__device__ __forceinline__ unsigned int pack2(float a, float b) {
    return (unsigned)f2bf(a) | ((unsigned)f2bf(b) << 16);
}

// ---------------- fused prep: cast x->bf16, weight transpose-casts, u=Wg_h@att, degree count
__global__ __launch_bounds__(256) void k_prep(const float* __restrict__ x,
                                              unsigned short* __restrict__ xb,
                                              const float* __restrict__ Wg, unsigned short* __restrict__ WgT,
                                              const float* __restrict__ Wm, unsigned short* __restrict__ WmT,
                                              const float* __restrict__ W1, unsigned short* __restrict__ W1T,
                                              const float* __restrict__ W2, unsigned short* __restrict__ W2T,
                                              const float* __restrict__ att_s,
                                              const float* __restrict__ att_d,
                                              float* __restrict__ U,
                                              const int* __restrict__ dst, int* __restrict__ cnt,
                                              int n, int E) {
    const int t = threadIdx.x;
    int b = blockIdx.x;
    const int nCast = (n * FD / 8 + 255) / 256;
    const int nT1 = (FD * HF / 4 + 255) / 256;
    const int nT3 = (FD * FD / 4 + 255) / 256;
    const int nU = 4;
    if (b < nCast) {
        int i = b * 256 + t;
        if (i < n * FD / 8) {
            const float4* x4 = reinterpret_cast<const float4*>(x);
            float4 v0 = x4[i * 2], v1 = x4[i * 2 + 1];
            uint4 o;
            o.x = pack2(v0.x, v0.y); o.y = pack2(v0.z, v0.w);
            o.z = pack2(v1.x, v1.y); o.w = pack2(v1.z, v1.w);
            reinterpret_cast<uint4*>(xb)[i] = o;
        }
        return;
    }
    b -= nCast;
    if (b < nT1) {   // WgT[512][128] <- Wg[128][512]
        int i4 = (b * 256 + t) * 4;
        if (i4 < FD * HF) {
            int nn = i4 >> 7, k = i4 & 127;
            uint2 o;
            o.x = pack2(Wg[(size_t)k * HF + nn], Wg[(size_t)(k + 1) * HF + nn]);
            o.y = pack2(Wg[(size_t)(k + 2) * HF + nn], Wg[(size_t)(k + 3) * HF + nn]);
            *reinterpret_cast<uint2*>(&WgT[i4]) = o;
        }
        return;
    }
    b -= nT1;
    if (b < nT1) {   // WmT[128][512] <- Wm[512][128]
        int i4 = (b * 256 + t) * 4;
        if (i4 < HF * FD) {
            int nn = i4 >> 9, k = i4 & 511;
            uint2 o;
            o.x = pack2(Wm[(size_t)k * FD + nn], Wm[(size_t)(k + 1) * FD + nn]);
            o.y = pack2(Wm[(size_t)(k + 2) * FD + nn], Wm[(size_t)(k + 3) * FD + nn]);
            *reinterpret_cast<uint2*>(&WmT[i4]) = o;
        }
        return;
    }
    b -= nT1;
    if (b < nT3) {   // W1T[128][128]
        int i4 = (b * 256 + t) * 4;
        if (i4 < FD * FD) {
            int nn = i4 >> 7, k = i4 & 127;
            uint2 o;
            o.x = pack2(W1[(size_t)k * FD + nn], W1[(size_t)(k + 1) * FD + nn]);
            o.y = pack2(W1[(size_t)(k + 2) * FD + nn], W1[(size_t)(k + 3) * FD + nn]);
            *reinterpret_cast<uint2*>(&W1T[i4]) = o;
        }
        return;
    }
    b -= nT3;
    if (b < nT3) {   // W2T[128][128]
        int i4 = (b * 256 + t) * 4;
        if (i4 < FD * FD) {
            int nn = i4 >> 7, k = i4 & 127;
            uint2 o;
            o.x = pack2(W2[(size_t)k * FD + nn], W2[(size_t)(k + 1) * FD + nn]);
            o.y = pack2(W2[(size_t)(k + 2) * FD + nn], W2[(size_t)(k + 3) * FD + nn]);
            *reinterpret_cast<uint2*>(&W2T[i4]) = o;
        }
        return;
    }
    b -= nT3;
    if (b < nU) {    // U[0..511]=u_s[h][k], U[512..1023]=u_d[h][k]
        int idx = b * 256 + t;
        int type = idx >> 9, h = (idx >> 7) & 3, k = idx & 127;
        const float* att = type ? att_d : att_s;
        const float* wrow = &Wg[(size_t)k * HF + h * FD];
        const float* arow = &att[h * FD];
        float s = 0.f;
#pragma unroll 4
        for (int j = 0; j < FD; ++j) s += wrow[j] * arow[j];
        U[idx] = s;
        return;
    }
    b -= nU;
    {
        int i = b * 256 + t;
        if (i < E) atomicAdd(&cnt[dst[i]], 1);
    }
}

// ---------------- a_s[n,h] = x[n]·u_s[h], a_d[n,h] = x[n]·u_d[h]   (fp32)
__global__ __launch_bounds__(256) void k_alog(const float* __restrict__ x,
                                              const float* __restrict__ U,
                                              float* __restrict__ a_s,
                                              float* __restrict__ a_d, int n) {
    int idx = blockIdx.x * 256 + threadIdx.x;
    int node = idx >> 2, h = idx & 3;
    if (node >= n) return;
    const float4* xr = reinterpret_cast<const float4*>(&x[(size_t)node * FD]);
    const float4* us = reinterpret_cast<const float4*>(&U[h * FD]);
    const float4* ud = reinterpret_cast<const float4*>(&U[512 + h * FD]);
    float ps = 0.f, pd = 0.f;
#pragma unroll 8
    for (int j = 0; j < 32; ++j) {
        float4 v = xr[j], a = us[j], bb = ud[j];
        ps += v.x * a.x + v.y * a.y + v.z * a.z + v.w * a.w;
        pd += v.x * bb.x + v.y * bb.y + v.z * bb.z + v.w * bb.w;
    }
    a_s[node * NH + h] = ps;
    a_d[node * NH + h] = pd;
}

// ---------------- multi-block exclusive scan (3 phases)
__global__ __launch_bounds__(1024) void k_scanA(const int* __restrict__ cnt,
                                                int* __restrict__ bsum, int n) {
    __shared__ int wtot[16];
    const int b = blockIdx.x, t = threadIdx.x;
    const int lane = t & 63, wid = t >> 6;
    const int idx = b * 4096 + t * 4;
    int s = 0;
    if (idx + 3 < n) {
        int4 v = *reinterpret_cast<const int4*>(&cnt[idx]);
        s = v.x + v.y + v.z + v.w;
    } else {
        for (int j = 0; j < 4; ++j) if (idx + j < n) s += cnt[idx + j];
    }
#pragma unroll
    for (int d = 1; d < 64; d <<= 1) s += __shfl_xor(s, d);
    if (lane == 0) wtot[wid] = s;
    __syncthreads();
    if (t == 0) {
        int tot = 0;
#pragma unroll
        for (int i = 0; i < 16; ++i) tot += wtot[i];
        bsum[b] = tot;
    }
}

__global__ void k_scanB(const int* __restrict__ bsum, int* __restrict__ bpre, int nb) {
    const int l = threadIdx.x;
    int v = (l < nb) ? bsum[l] : 0;
    int incl = v;
#pragma unroll
    for (int d = 1; d < 64; d <<= 1) {
        int o = __shfl_up(incl, d);
        if (l >= d) incl += o;
    }
    if (l < nb) bpre[l] = incl - v;
}

__global__ __launch_bounds__(1024) void k_scanC(const int* __restrict__ cnt,
                                                const int* __restrict__ bpre,
                                                int* __restrict__ off,
                                                int* __restrict__ cur, int n) {
    __shared__ int wtot[16];
    const int b = blockIdx.x, t = threadIdx.x;
    const int lane = t & 63, wid = t >> 6;
    const int idx = b * 4096 + t * 4;
    int4 v = make_int4(0, 0, 0, 0);
    if (idx + 3 < n) v = *reinterpret_cast<const int4*>(&cnt[idx]);
    else {
        if (idx < n) v.x = cnt[idx];
        if (idx + 1 < n) v.y = cnt[idx + 1];
        if (idx + 2 < n) v.z = cnt[idx + 2];
        if (idx + 3 < n) v.w = cnt[idx + 3];
    }
    const int p1 = v.x, p2 = p1 + v.y, p3 = p2 + v.z, ts = p3 + v.w;
    int incl = ts;
#pragma unroll
    for (int d = 1; d < 64; d <<= 1) {
        int o = __shfl_up(incl, d);
        if (lane >= d) incl += o;
    }
    if (lane == 63) wtot[wid] = incl;
    __syncthreads();
    int wbase = 0;
#pragma unroll
    for (int i = 0; i < 16; ++i) if (i < wid) wbase += wtot[i];
    const int base = bpre[b] + wbase + (incl - ts);
    if (idx < n)     { cur[idx] = base;          off[idx + 1] = base + p1; }
    if (idx + 1 < n) { cur[idx + 1] = base + p1; off[idx + 2] = base + p2; }
    if (idx + 2 < n) { cur[idx + 2] = base + p2; off[idx + 3] = base + p3; }
    if (idx + 3 < n) { cur[idx + 3] = base + p3; off[idx + 4] = base + ts; }
    if (b == 0 && t == 0) off[0] = 0;
}

// ---------------- scatter edges into CSR slots, with leaky(0.2) logits
__global__ __launch_bounds__(256) void k_scatter(const int* __restrict__ es,
                                                 const int* __restrict__ ed,
                                                 const float* __restrict__ a_s,
                                                 const float* __restrict__ a_d,
                                                 int* __restrict__ cur,
                                                 int* __restrict__ ssort,
                                                 float4* __restrict__ asort, int e) {
    int i = blockIdx.x * 256 + threadIdx.x;
    if (i >= e) return;
    int s = es[i], d = ed[i];
    const float4 as = *reinterpret_cast<const float4*>(&a_s[(size_t)s * NH]);
    const float4 ad = *reinterpret_cast<const float4*>(&a_d[(size_t)d * NH]);
    float4 al;
    al.x = lrelu(as.x + ad.x, 0.2f);
    al.y = lrelu(as.y + ad.y, 0.2f);
    al.z = lrelu(as.z + ad.z, 0.2f);
    al.w = lrelu(as.w + ad.w, 0.2f);
    int pos = atomicAdd(&cur[d], 1);
    ssort[pos] = s;
    asort[pos] = al;
}

// ---------------- per-node (one wave) aggregation in x-space -> agg bf16 [n][h*128+k]
__global__ __launch_bounds__(256) void k_aggr2(const unsigned short* __restrict__ xb,
                                               const float* __restrict__ a_s,
                                               const float* __restrict__ a_d,
                                               const int* __restrict__ off,
                                               const int* __restrict__ ssort,
                                               const float* __restrict__ asort,
                                               unsigned short* __restrict__ agg, int n) {
    const int w = threadIdx.x >> 6, l = threadIdx.x & 63;
    const int node = blockIdx.x * 4 + w;
    if (node >= n) return;
    const int e16 = l & 15;
    const int o0 = off[node], deg = off[node + 1] - o0;

    float wS[4];
#pragma unroll
    for (int hh = 0; hh < 4; ++hh)
        wS[hh] = __expf(lrelu(a_s[node * NH + hh] + a_d[node * NH + hh], 0.2f));

    float acc[8];   // [h][2 feats]
    {
        unsigned int ux = *reinterpret_cast<const unsigned int*>(&xb[(size_t)node * FD + 2 * l]);
        float f0 = __uint_as_float(ux << 16);
        float f1 = __uint_as_float(ux & 0xffff0000u);
#pragma unroll
        for (int hh = 0; hh < 4; ++hh) { acc[hh * 2] = f0 * wS[hh]; acc[hh * 2 + 1] = f1 * wS[hh]; }
    }
    const int* sso = ssort + o0;
    const float* aso = asort + (size_t)o0 * 4 + (l >> 4);
    float sswl = 0.f;

    int base = 0;
    int sidx = 0; float wl = 0.f;
    if (16 <= deg) { sidx = sso[e16]; wl = __expf(aso[4 * e16]); }
    while (base + 16 <= deg) {
        const int nb2 = base + 16;
        int sN = 0; float wN = 0.f;
        if (nb2 + 16 <= deg) { sN = sso[nb2 + e16]; wN = __expf(aso[4 * (nb2 + e16)]); }
        sswl += wl;
#pragma unroll
        for (int e = 0; e < 16; ++e) {
            int s = __shfl(sidx, e);
            float w0 = __shfl(wl, e);
            float w1 = __shfl(wl, 16 + e);
            float w2 = __shfl(wl, 32 + e);
            float w3 = __shfl(wl, 48 + e);
            unsigned int u = *reinterpret_cast<const unsigned int*>(&xb[(size_t)s * FD + 2 * l]);
            float f0 = __uint_as_float(u << 16);
            float f1 = __uint_as_float(u & 0xffff0000u);
            acc[0] += f0 * w0; acc[1] += f1 * w0;
            acc[2] += f0 * w1; acc[3] += f1 * w1;
            acc[4] += f0 * w2; acc[5] += f1 * w2;
            acc[6] += f0 * w3; acc[7] += f1 * w3;
        }
        sidx = sN; wl = wN; base = nb2;
    }
    const int rem = deg - base;
    if (rem > 0) {
        int s2 = 0; float w2l = 0.f;
        if (e16 < rem) { s2 = sso[base + e16]; w2l = __expf(aso[4 * (base + e16)]); }
        sswl += w2l;
        for (int e = 0; e < rem; ++e) {
            int s = __shfl(s2, e);
            float w0 = __shfl(w2l, e);
            float w1 = __shfl(w2l, 16 + e);
            float w2 = __shfl(w2l, 32 + e);
            float w3 = __shfl(w2l, 48 + e);
            unsigned int u = *reinterpret_cast<const unsigned int*>(&xb[(size_t)s * FD + 2 * l]);
            float f0 = __uint_as_float(u << 16);
            float f1 = __uint_as_float(u & 0xffff0000u);
            acc[0] += f0 * w0; acc[1] += f1 * w0;
            acc[2] += f0 * w1; acc[3] += f1 * w1;
            acc[4] += f0 * w2; acc[5] += f1 * w2;
            acc[6] += f0 * w3; acc[7] += f1 * w3;
        }
    }
#pragma unroll
    for (int d = 1; d < 16; d <<= 1) sswl += __shfl_xor(sswl, d);
    float inv[4];
#pragma unroll
    for (int hh = 0; hh < 4; ++hh) inv[hh] = 1.f / (__shfl(sswl, hh * 16) + wS[hh]);
#pragma unroll
    for (int hh = 0; hh < 4; ++hh) {
        unsigned int o = pack2(acc[hh * 2] * inv[hh], acc[hh * 2 + 1] * inv[hh]);
        *reinterpret_cast<unsigned int*>(&agg[(size_t)node * HF + hh * FD + 2 * l]) = o;
    }
}

// ---------------- fused tail with LDS-staged weights:
// hm = sum_h lrelu(agg_h@Wg_h+bg_h)@Wm_h + bm + x; out = lrelu(hm@W1+b1)@W2 + b2 + hm.
// WL: one 128x128 weight tile, cooperatively staged (B from LDS, ~12cy vs ~300cy L2).
// tS rows are wave-private (each wave reads only rows it wrote) -> no barriers for tS.
__global__ __launch_bounds__(256, 3) void k_tail(const unsigned short* __restrict__ agg,
                                                 const unsigned short* __restrict__ WgT,
                                                 const float* __restrict__ biasg,
                                                 const unsigned short* __restrict__ WmT,
                                                 const float* __restrict__ bm,
                                                 const float* __restrict__ x,
                                                 const unsigned short* __restrict__ W1T,
                                                 const float* __restrict__ b1,
                                                 const unsigned short* __restrict__ W2T,
                                                 const float* __restrict__ b2,
                                                 float* __restrict__ out, int n) {
    __shared__ unsigned short WL[128][132];  // 33 KB, pad->2-way banks max
    __shared__ unsigned short tS[64][136];   // 17.4 KB bridge
    const int tid = threadIdx.x;
    const int m0 = blockIdx.x * 64;
    const int wv = tid >> 6, l = tid & 63;
    const int rA = l & 15;
    const int kg = (l >> 4) * 8;
    const int mw = m0 + wv * 16;
    const int amr = min(mw + rA, n - 1);
    const int lr0 = wv * 16 + (l >> 4) * 4;
    const int sr = tid >> 4, sc = (tid & 15) * 8;   // staging: thread -> (row lane, col)

    v4f hma[8];
#pragma unroll
    for (int t = 0; t < 8; ++t) hma[t] = (v4f){0.f, 0.f, 0.f, 0.f};

#pragma unroll 1
    for (int h = 0; h < 4; ++h) {
        // ---- stage WgT_h -> WL
#pragma unroll
        for (int rnd = 0; rnd < 8; ++rnd) {
            int r = rnd * 16 + sr;
            *reinterpret_cast<short8*>(&WL[r][sc]) =
                *reinterpret_cast<const short8*>(&WgT[((size_t)h * FD + r) * FD + sc]);
        }
        __syncthreads();
        // ---- t_h = lrelu(agg_h @ Wg_h + bg_h)
        v4f acc[8];
#pragma unroll
        for (int t = 0; t < 8; ++t) acc[t] = (v4f){0.f, 0.f, 0.f, 0.f};
#pragma unroll
        for (int kk = 0; kk < 4; ++kk) {
            short8 a = *reinterpret_cast<const short8*>(
                &agg[(size_t)amr * HF + h * FD + kk * 32 + kg]);
#pragma unroll
            for (int nt = 0; nt < 8; ++nt) {
                short8 b = *reinterpret_cast<const short8*>(&WL[nt * 16 + rA][kk * 32 + kg]);
                acc[nt] = __builtin_amdgcn_mfma_f32_16x16x32_bf16(a, b, acc[nt], 0, 0, 0);
            }
        }
#pragma unroll
        for (int nt = 0; nt < 8; ++nt) {
            const int col = nt * 16 + rA;
            const float bv = biasg[h * FD + col];
#pragma unroll
            for (int i = 0; i < 4; ++i)
                tS[lr0 + i][col] = f2bf(lrelu(acc[nt][i] + bv, 0.01f));
        }
        __syncthreads();   // all WL(Wg) reads done
        // ---- stage WmT_h slice -> WL
#pragma unroll
        for (int rnd = 0; rnd < 8; ++rnd) {
            int r = rnd * 16 + sr;
            *reinterpret_cast<short8*>(&WL[r][sc]) =
                *reinterpret_cast<const short8*>(&WmT[(size_t)r * HF + h * FD + sc]);
        }
        __syncthreads();
        // ---- hm += t_h @ Wm_h
#pragma unroll
        for (int kk = 0; kk < 4; ++kk) {
            short8 a = *reinterpret_cast<const short8*>(&tS[wv * 16 + rA][kk * 32 + kg]);
#pragma unroll
            for (int nt = 0; nt < 8; ++nt) {
                short8 b = *reinterpret_cast<const short8*>(&WL[nt * 16 + rA][kk * 32 + kg]);
                hma[nt] = __builtin_amdgcn_mfma_f32_16x16x32_bf16(a, b, hma[nt], 0, 0, 0);
            }
        }
        __syncthreads();   // all WL(Wm) reads done before next stage
    }

    // ---- hm finalize: + bm + x (fp32 regs for exact residual; bf16 to tS)
    float hmr[8][4];
#pragma unroll
    for (int nt = 0; nt < 8; ++nt) {
        const int col = nt * 16 + rA;
        const float bv = bm[col];
#pragma unroll
        for (int i = 0; i < 4; ++i) {
            const int r = min(mw + (l >> 4) * 4 + i, n - 1);
            float v = hma[nt][i] + bv + x[(size_t)r * FD + col];
            hmr[nt][i] = v;
            tS[lr0 + i][col] = f2bf(v);
        }
    }
    // ---- stage W1T -> WL (last head's barrier already passed; WL free)
#pragma unroll
    for (int rnd = 0; rnd < 8; ++rnd) {
        int r = rnd * 16 + sr;
        *reinterpret_cast<short8*>(&WL[r][sc]) =
            *reinterpret_cast<const short8*>(&W1T[(size_t)r * FD + sc]);
    }
    __syncthreads();
    // ---- FFN1: t2 = lrelu(hm @ W1 + b1)
    v4f acc[8];
#pragma unroll
    for (int t = 0; t < 8; ++t) acc[t] = (v4f){0.f, 0.f, 0.f, 0.f};
#pragma unroll
    for (int kk = 0; kk < 4; ++kk) {
        short8 a = *reinterpret_cast<const short8*>(&tS[wv * 16 + rA][kk * 32 + kg]);
#pragma unroll
        for (int nt = 0; nt < 8; ++nt) {
            short8 b = *reinterpret_cast<const short8*>(&WL[nt * 16 + rA][kk * 32 + kg]);
            acc[nt] = __builtin_amdgcn_mfma_f32_16x16x32_bf16(a, b, acc[nt], 0, 0, 0);
        }
    }
#pragma unroll
    for (int nt = 0; nt < 8; ++nt) {
        const int col = nt * 16 + rA;
        const float bv = b1[col];
#pragma unroll
        for (int i = 0; i < 4; ++i)
            tS[lr0 + i][col] = f2bf(lrelu(acc[nt][i] + bv, 0.01f));
    }
    __syncthreads();   // WL(W1) reads done
    // ---- stage W2T -> WL
#pragma unroll
    for (int rnd = 0; rnd < 8; ++rnd) {
        int r = rnd * 16 + sr;
        *reinterpret_cast<short8*>(&WL[r][sc]) =
            *reinterpret_cast<const short8*>(&W2T[(size_t)r * FD + sc]);
    }
    __syncthreads();
    // ---- FFN2: out = t2 @ W2 + b2 + hm
#pragma unroll
    for (int t = 0; t < 8; ++t) acc[t] = (v4f){0.f, 0.f, 0.f, 0.f};
#pragma unroll
    for (int kk = 0; kk < 4; ++kk) {
        short8 a = *reinterpret_cast<const short8*>(&tS[wv * 16 + rA][kk * 32 + kg]);
#pragma unroll
        for (int nt = 0; nt < 8; ++nt) {
            short8 b = *reinterpret_cast<const short8*>(&WL[nt * 16 + rA][kk * 32 + kg]);
            acc[nt] = __builtin_amdgcn_mfma_f32_16x16x32_bf16(a, b, acc[nt], 0, 0, 0);
        }
    }
#pragma unroll
    for (int nt = 0; nt < 8; ++nt) {
        const int col = nt * 16 + rA;
        const float bv = b2[col];
#pragma unroll
        for (int i = 0; i < 4; ++i) {
            const int r = mw + (l >> 4) * 4 + i;
            if (r < n)
                out[(size_t)r * FD + col] = acc[nt][i] + bv + hmr[nt][i];
        }
    }
}

extern "C" void kernel_launch(void* const* d_in, const int* in_sizes, int n_in,
                              void* d_out, int out_size, void* d_ws, size_t ws_size,
                              hipStream_t stream) {
    const float* x     = (const float*)d_in[0];
    const int*   ei    = (const int*)d_in[1];
    const float* Wg    = (const float*)d_in[2];
    const float* att_s = (const float*)d_in[3];
    const float* att_d = (const float*)d_in[4];
    const float* biasg = (const float*)d_in[5];
    const float* Wm    = (const float*)d_in[6];
    const float* bm    = (const float*)d_in[7];
    const float* W1    = (const float*)d_in[8];
    const float* b1    = (const float*)d_in[9];
    const float* W2    = (const float*)d_in[10];
    const float* b2    = (const float*)d_in[11];
    float* out = (float*)d_out;

    const int n = in_sizes[0] / FD;
    const int E = in_sizes[1] / 2;
    const int* esrc = ei;
    const int* edst = ei + E;

    char* w = (char*)d_ws;
    size_t o = 0;
    auto alloc = [&](size_t b) { void* p = w + o; o = (o + b + 255) & ~(size_t)255; return p; };
    unsigned short* x_b  = (unsigned short*)alloc((size_t)n * FD * 2);
    unsigned short* WgT  = (unsigned short*)alloc((size_t)FD * HF * 2);
    unsigned short* WmT  = (unsigned short*)alloc((size_t)HF * FD * 2);
    unsigned short* W1T  = (unsigned short*)alloc((size_t)FD * FD * 2);
    unsigned short* W2T  = (unsigned short*)alloc((size_t)FD * FD * 2);
    float*          U    = (float*)alloc(1024 * 4);
    unsigned short* aggb = (unsigned short*)alloc((size_t)n * HF * 2);
    float* a_s   = (float*)alloc((size_t)n * NH * 4);
    float* a_d   = (float*)alloc((size_t)n * NH * 4);
    int*   cnt   = (int*)alloc((size_t)n * 4);
    int*   offs  = (int*)alloc((size_t)(n + 1) * 4);
    int*   cur   = (int*)alloc((size_t)n * 4);
    int*   ssort = (int*)alloc((size_t)E * 4);
    float* asort = (float*)alloc((size_t)E * 16);
    int*   bsum  = (int*)alloc(256 * 4);
    int*   bpre  = (int*)alloc(256 * 4);

    hipMemsetAsync(cnt, 0, (size_t)n * 4, stream);

    const int nCast = (n * FD / 8 + 255) / 256;
    const int nT1 = (FD * HF / 4 + 255) / 256;
    const int nT3 = (FD * FD / 4 + 255) / 256;
    const int nU = 4;
    const int nCnt = (E + 255) / 256;
    k_prep<<<nCast + 2 * nT1 + 2 * nT3 + nU + nCnt, 256, 0, stream>>>(
        x, x_b, Wg, WgT, Wm, WmT, W1, W1T, W2, W2T, att_s, att_d, U, edst, cnt, n, E);

    k_alog<<<(n * 4 + 255) / 256, 256, 0, stream>>>(x, U, a_s, a_d, n);

    const int SB = (n + 4095) / 4096;
    k_scanA<<<SB, 1024, 0, stream>>>(cnt, bsum, n);
    k_scanB<<<1, 64, 0, stream>>>(bsum, bpre, SB);
    k_scanC<<<SB, 1024, 0, stream>>>(cnt, bpre, offs, cur, n);
    k_scatter<<<(E + 255) / 256, 256, 0, stream>>>(esrc, edst, a_s, a_d, cur, ssort,
                                                   (float4*)asort, E);
    k_aggr2<<<(n + 3) / 4, 256, 0, stream>>>(x_b, a_s, a_d, offs, ssort, asort, aggb, n);

    const int mb = (n + 63) / 64;
    k_tail<<<mb, 256, 0, stream>>>(aggb, WgT, biasg, WmT, bm, x, W1T, b1, W2T, b2, out, n);
}

// Round 8
// 272.191 us; speedup vs baseline: 1.4344x; 1.1580x over previous
//
#include <hip/hip_runtime.h>

#define FD 128
#define NH 4
#define HF 512

typedef __attribute__((ext_vector_type(8))) short short8;
typedef __attribute__((ext_vector_type(4))) float v4f;

__device__ __forceinline__ float lrelu(float x, float s) { return x > 0.f ? x : s * x; }

__device__ __forceinline__ unsigned short f2bf(float f) {
    unsigned int u = __float_as_uint(f);
    u += 0x7FFFu + ((u >> 16) & 1u);          // RNE
    return (unsigned short)(u >> 16);
}
__device__ __forceinline__ unsigned int pack2(float a, float b) {
    return (unsigned)f2bf(a) | ((unsigned)f2bf(b) << 16);
}

// ---------------- fused prep: cast x->bf16, weight transpose-casts, u=Wg_h@att, degree count
__global__ __launch_bounds__(256) void k_prep(const float* __restrict__ x,
                                              unsigned short* __restrict__ xb,
                                              const float* __restrict__ Wg, unsigned short* __restrict__ WgT,
                                              const float* __restrict__ Wm, unsigned short* __restrict__ WmT,
                                              const float* __restrict__ W1, unsigned short* __restrict__ W1T,
                                              const float* __restrict__ W2, unsigned short* __restrict__ W2T,
                                              const float* __restrict__ att_s,
                                              const float* __restrict__ att_d,
                                              float* __restrict__ U,
                                              const int* __restrict__ dst, int* __restrict__ cnt,
                                              int n, int E) {
    const int t = threadIdx.x;
    int b = blockIdx.x;
    const int nCast = (n * FD / 8 + 255) / 256;
    const int nT1 = (FD * HF / 4 + 255) / 256;
    const int nT3 = (FD * FD / 4 + 255) / 256;
    const int nU = 4;
    if (b < nCast) {
        int i = b * 256 + t;
        if (i < n * FD / 8) {
            const float4* x4 = reinterpret_cast<const float4*>(x);
            float4 v0 = x4[i * 2], v1 = x4[i * 2 + 1];
            uint4 o;
            o.x = pack2(v0.x, v0.y); o.y = pack2(v0.z, v0.w);
            o.z = pack2(v1.x, v1.y); o.w = pack2(v1.z, v1.w);
            reinterpret_cast<uint4*>(xb)[i] = o;
        }
        return;
    }
    b -= nCast;
    if (b < nT1) {   // WgT[512][128] <- Wg[128][512]
        int i4 = (b * 256 + t) * 4;
        if (i4 < FD * HF) {
            int nn = i4 >> 7, k = i4 & 127;
            uint2 o;
            o.x = pack2(Wg[(size_t)k * HF + nn], Wg[(size_t)(k + 1) * HF + nn]);
            o.y = pack2(Wg[(size_t)(k + 2) * HF + nn], Wg[(size_t)(k + 3) * HF + nn]);
            *reinterpret_cast<uint2*>(&WgT[i4]) = o;
        }
        return;
    }
    b -= nT1;
    if (b < nT1) {   // WmT[128][512] <- Wm[512][128]
        int i4 = (b * 256 + t) * 4;
        if (i4 < HF * FD) {
            int nn = i4 >> 9, k = i4 & 511;
            uint2 o;
            o.x = pack2(Wm[(size_t)k * FD + nn], Wm[(size_t)(k + 1) * FD + nn]);
            o.y = pack2(Wm[(size_t)(k + 2) * FD + nn], Wm[(size_t)(k + 3) * FD + nn]);
            *reinterpret_cast<uint2*>(&WmT[i4]) = o;
        }
        return;
    }
    b -= nT1;
    if (b < nT3) {   // W1T[128][128]
        int i4 = (b * 256 + t) * 4;
        if (i4 < FD * FD) {
            int nn = i4 >> 7, k = i4 & 127;
            uint2 o;
            o.x = pack2(W1[(size_t)k * FD + nn], W1[(size_t)(k + 1) * FD + nn]);
            o.y = pack2(W1[(size_t)(k + 2) * FD + nn], W1[(size_t)(k + 3) * FD + nn]);
            *reinterpret_cast<uint2*>(&W1T[i4]) = o;
        }
        return;
    }
    b -= nT3;
    if (b < nT3) {   // W2T[128][128]
        int i4 = (b * 256 + t) * 4;
        if (i4 < FD * FD) {
            int nn = i4 >> 7, k = i4 & 127;
            uint2 o;
            o.x = pack2(W2[(size_t)k * FD + nn], W2[(size_t)(k + 1) * FD + nn]);
            o.y = pack2(W2[(size_t)(k + 2) * FD + nn], W2[(size_t)(k + 3) * FD + nn]);
            *reinterpret_cast<uint2*>(&W2T[i4]) = o;
        }
        return;
    }
    b -= nT3;
    if (b < nU) {    // U[0..511]=u_s[h][k], U[512..1023]=u_d[h][k]
        int idx = b * 256 + t;
        int type = idx >> 9, h = (idx >> 7) & 3, k = idx & 127;
        const float* att = type ? att_d : att_s;
        const float* wrow = &Wg[(size_t)k * HF + h * FD];
        const float* arow = &att[h * FD];
        float s = 0.f;
#pragma unroll 4
        for (int j = 0; j < FD; ++j) s += wrow[j] * arow[j];
        U[idx] = s;
        return;
    }
    b -= nU;
    {
        int i = b * 256 + t;
        if (i < E) atomicAdd(&cnt[dst[i]], 1);
    }
}

// ---------------- a_s[n,h] = x[n]·u_s[h], a_d[n,h] = x[n]·u_d[h]   (fp32)
__global__ __launch_bounds__(256) void k_alog(const float* __restrict__ x,
                                              const float* __restrict__ U,
                                              float* __restrict__ a_s,
                                              float* __restrict__ a_d, int n) {
    int idx = blockIdx.x * 256 + threadIdx.x;
    int node = idx >> 2, h = idx & 3;
    if (node >= n) return;
    const float4* xr = reinterpret_cast<const float4*>(&x[(size_t)node * FD]);
    const float4* us = reinterpret_cast<const float4*>(&U[h * FD]);
    const float4* ud = reinterpret_cast<const float4*>(&U[512 + h * FD]);
    float ps = 0.f, pd = 0.f;
#pragma unroll 8
    for (int j = 0; j < 32; ++j) {
        float4 v = xr[j], a = us[j], bb = ud[j];
        ps += v.x * a.x + v.y * a.y + v.z * a.z + v.w * a.w;
        pd += v.x * bb.x + v.y * bb.y + v.z * bb.z + v.w * bb.w;
    }
    a_s[node * NH + h] = ps;
    a_d[node * NH + h] = pd;
}

// ---------------- multi-block exclusive scan (3 phases)
__global__ __launch_bounds__(1024) void k_scanA(const int* __restrict__ cnt,
                                                int* __restrict__ bsum, int n) {
    __shared__ int wtot[16];
    const int b = blockIdx.x, t = threadIdx.x;
    const int lane = t & 63, wid = t >> 6;
    const int idx = b * 4096 + t * 4;
    int s = 0;
    if (idx + 3 < n) {
        int4 v = *reinterpret_cast<const int4*>(&cnt[idx]);
        s = v.x + v.y + v.z + v.w;
    } else {
        for (int j = 0; j < 4; ++j) if (idx + j < n) s += cnt[idx + j];
    }
#pragma unroll
    for (int d = 1; d < 64; d <<= 1) s += __shfl_xor(s, d);
    if (lane == 0) wtot[wid] = s;
    __syncthreads();
    if (t == 0) {
        int tot = 0;
#pragma unroll
        for (int i = 0; i < 16; ++i) tot += wtot[i];
        bsum[b] = tot;
    }
}

__global__ void k_scanB(const int* __restrict__ bsum, int* __restrict__ bpre, int nb) {
    const int l = threadIdx.x;
    int v = (l < nb) ? bsum[l] : 0;
    int incl = v;
#pragma unroll
    for (int d = 1; d < 64; d <<= 1) {
        int o = __shfl_up(incl, d);
        if (l >= d) incl += o;
    }
    if (l < nb) bpre[l] = incl - v;
}

__global__ __launch_bounds__(1024) void k_scanC(const int* __restrict__ cnt,
                                                const int* __restrict__ bpre,
                                                int* __restrict__ off,
                                                int* __restrict__ cur, int n) {
    __shared__ int wtot[16];
    const int b = blockIdx.x, t = threadIdx.x;
    const int lane = t & 63, wid = t >> 6;
    const int idx = b * 4096 + t * 4;
    int4 v = make_int4(0, 0, 0, 0);
    if (idx + 3 < n) v = *reinterpret_cast<const int4*>(&cnt[idx]);
    else {
        if (idx < n) v.x = cnt[idx];
        if (idx + 1 < n) v.y = cnt[idx + 1];
        if (idx + 2 < n) v.z = cnt[idx + 2];
        if (idx + 3 < n) v.w = cnt[idx + 3];
    }
    const int p1 = v.x, p2 = p1 + v.y, p3 = p2 + v.z, ts = p3 + v.w;
    int incl = ts;
#pragma unroll
    for (int d = 1; d < 64; d <<= 1) {
        int o = __shfl_up(incl, d);
        if (lane >= d) incl += o;
    }
    if (lane == 63) wtot[wid] = incl;
    __syncthreads();
    int wbase = 0;
#pragma unroll
    for (int i = 0; i < 16; ++i) if (i < wid) wbase += wtot[i];
    const int base = bpre[b] + wbase + (incl - ts);
    if (idx < n)     { cur[idx] = base;          off[idx + 1] = base + p1; }
    if (idx + 1 < n) { cur[idx + 1] = base + p1; off[idx + 2] = base + p2; }
    if (idx + 2 < n) { cur[idx + 2] = base + p2; off[idx + 3] = base + p3; }
    if (idx + 3 < n) { cur[idx + 3] = base + p3; off[idx + 4] = base + ts; }
    if (b == 0 && t == 0) off[0] = 0;
}

// ---------------- scatter edges into CSR slots, with leaky(0.2) logits
__global__ __launch_bounds__(256) void k_scatter(const int* __restrict__ es,
                                                 const int* __restrict__ ed,
                                                 const float* __restrict__ a_s,
                                                 const float* __restrict__ a_d,
                                                 int* __restrict__ cur,
                                                 int* __restrict__ ssort,
                                                 float4* __restrict__ asort, int e) {
    int i = blockIdx.x * 256 + threadIdx.x;
    if (i >= e) return;
    int s = es[i], d = ed[i];
    const float4 as = *reinterpret_cast<const float4*>(&a_s[(size_t)s * NH]);
    const float4 ad = *reinterpret_cast<const float4*>(&a_d[(size_t)d * NH]);
    float4 al;
    al.x = lrelu(as.x + ad.x, 0.2f);
    al.y = lrelu(as.y + ad.y, 0.2f);
    al.z = lrelu(as.z + ad.z, 0.2f);
    al.w = lrelu(as.w + ad.w, 0.2f);
    int pos = atomicAdd(&cur[d], 1);
    ssort[pos] = s;
    asort[pos] = al;
}

// ---------------- per-node (one wave) aggregation in x-space -> agg bf16 [n][h*128+k]
__global__ __launch_bounds__(256) void k_aggr2(const unsigned short* __restrict__ xb,
                                               const float* __restrict__ a_s,
                                               const float* __restrict__ a_d,
                                               const int* __restrict__ off,
                                               const int* __restrict__ ssort,
                                               const float* __restrict__ asort,
                                               unsigned short* __restrict__ agg, int n) {
    const int w = threadIdx.x >> 6, l = threadIdx.x & 63;
    const int node = blockIdx.x * 4 + w;
    if (node >= n) return;
    const int e16 = l & 15;
    const int o0 = off[node], deg = off[node + 1] - o0;

    float wS[4];
#pragma unroll
    for (int hh = 0; hh < 4; ++hh)
        wS[hh] = __expf(lrelu(a_s[node * NH + hh] + a_d[node * NH + hh], 0.2f));

    float acc[8];   // [h][2 feats]
    {
        unsigned int ux = *reinterpret_cast<const unsigned int*>(&xb[(size_t)node * FD + 2 * l]);
        float f0 = __uint_as_float(ux << 16);
        float f1 = __uint_as_float(ux & 0xffff0000u);
#pragma unroll
        for (int hh = 0; hh < 4; ++hh) { acc[hh * 2] = f0 * wS[hh]; acc[hh * 2 + 1] = f1 * wS[hh]; }
    }
    const int* sso = ssort + o0;
    const float* aso = asort + (size_t)o0 * 4 + (l >> 4);
    float sswl = 0.f;

    int base = 0;
    int sidx = 0; float wl = 0.f;
    if (16 <= deg) { sidx = sso[e16]; wl = __expf(aso[4 * e16]); }
    while (base + 16 <= deg) {
        const int nb2 = base + 16;
        int sN = 0; float wN = 0.f;
        if (nb2 + 16 <= deg) { sN = sso[nb2 + e16]; wN = __expf(aso[4 * (nb2 + e16)]); }
        sswl += wl;
#pragma unroll
        for (int e = 0; e < 16; ++e) {
            int s = __shfl(sidx, e);
            float w0 = __shfl(wl, e);
            float w1 = __shfl(wl, 16 + e);
            float w2 = __shfl(wl, 32 + e);
            float w3 = __shfl(wl, 48 + e);
            unsigned int u = *reinterpret_cast<const unsigned int*>(&xb[(size_t)s * FD + 2 * l]);
            float f0 = __uint_as_float(u << 16);
            float f1 = __uint_as_float(u & 0xffff0000u);
            acc[0] += f0 * w0; acc[1] += f1 * w0;
            acc[2] += f0 * w1; acc[3] += f1 * w1;
            acc[4] += f0 * w2; acc[5] += f1 * w2;
            acc[6] += f0 * w3; acc[7] += f1 * w3;
        }
        sidx = sN; wl = wN; base = nb2;
    }
    const int rem = deg - base;
    if (rem > 0) {
        int s2 = 0; float w2l = 0.f;
        if (e16 < rem) { s2 = sso[base + e16]; w2l = __expf(aso[4 * (base + e16)]); }
        sswl += w2l;
        for (int e = 0; e < rem; ++e) {
            int s = __shfl(s2, e);
            float w0 = __shfl(w2l, e);
            float w1 = __shfl(w2l, 16 + e);
            float w2 = __shfl(w2l, 32 + e);
            float w3 = __shfl(w2l, 48 + e);
            unsigned int u = *reinterpret_cast<const unsigned int*>(&xb[(size_t)s * FD + 2 * l]);
            float f0 = __uint_as_float(u << 16);
            float f1 = __uint_as_float(u & 0xffff0000u);
            acc[0] += f0 * w0; acc[1] += f1 * w0;
            acc[2] += f0 * w1; acc[3] += f1 * w1;
            acc[4] += f0 * w2; acc[5] += f1 * w2;
            acc[6] += f0 * w3; acc[7] += f1 * w3;
        }
    }
#pragma unroll
    for (int d = 1; d < 16; d <<= 1) sswl += __shfl_xor(sswl, d);
    float inv[4];
#pragma unroll
    for (int hh = 0; hh < 4; ++hh) inv[hh] = 1.f / (__shfl(sswl, hh * 16) + wS[hh]);
#pragma unroll
    for (int hh = 0; hh < 4; ++hh) {
        unsigned int o = pack2(acc[hh * 2] * inv[hh], acc[hh * 2 + 1] * inv[hh]);
        *reinterpret_cast<unsigned int*>(&agg[(size_t)node * HF + hh * FD + 2 * l]) = o;
    }
}

// ---------------- fused tail, M=128 / 512 threads / prefetch-pipelined weight staging.
// hm = sum_h lrelu(agg_h@Wg_h+bg_h)@Wm_h + bm + x; out = lrelu(hm@W1+b1)@W2 + b2 + hm.
// R: next weight tile prefetched to regs during current MFMA phase (T14 split).
// tS rows are wave-private (each wave reads only rows it wrote) -> no barriers for tS.
#define PREFETCH(BP, STRIDE) do {                                              \
    _Pragma("unroll")                                                          \
    for (int rnd = 0; rnd < 4; ++rnd) {                                        \
        int r_ = rnd * 32 + sr;                                                \
        R[rnd] = *reinterpret_cast<const short8*>(&(BP)[(size_t)r_ * (STRIDE) + sc]); \
    } } while (0)

#define COMMIT() do {                                                          \
    __syncthreads();                                                           \
    _Pragma("unroll")                                                          \
    for (int rnd = 0; rnd < 4; ++rnd) {                                        \
        int r_ = rnd * 32 + sr;                                                \
        *reinterpret_cast<short8*>(&WL[r_][sc]) = R[rnd];                      \
    }                                                                          \
    __syncthreads(); } while (0)

__global__ __launch_bounds__(512, 4) void k_tail(const unsigned short* __restrict__ agg,
                                                 const unsigned short* __restrict__ WgT,
                                                 const float* __restrict__ biasg,
                                                 const unsigned short* __restrict__ WmT,
                                                 const float* __restrict__ bm,
                                                 const float* __restrict__ x,
                                                 const unsigned short* __restrict__ W1T,
                                                 const float* __restrict__ b1,
                                                 const unsigned short* __restrict__ W2T,
                                                 const float* __restrict__ b2,
                                                 float* __restrict__ out, int n) {
    __shared__ unsigned short WL[128][132];   // 33.8 KB weight tile
    __shared__ unsigned short tS[128][132];   // 33.8 KB bridge
    const int tid = threadIdx.x;
    const int m0 = blockIdx.x * 128;
    const int wv = tid >> 6, l = tid & 63;
    const int rA = l & 15;
    const int kg = (l >> 4) * 8;
    const int mw = m0 + wv * 16;
    const int amr = min(mw + rA, n - 1);
    const int lr0 = wv * 16 + (l >> 4) * 4;
    const int sr = tid >> 4, sc = (tid & 15) * 8;   // staging: 32 rows x 256B per round

    short8 R[4];
    v4f hma[8];
#pragma unroll
    for (int t = 0; t < 8; ++t) hma[t] = (v4f){0.f, 0.f, 0.f, 0.f};

    PREFETCH(WgT, FD);          // R = Wg_0

#pragma unroll
    for (int h = 0; h < 4; ++h) {
        COMMIT();               // WL = Wg_h
        PREFETCH(WmT + h * FD, HF);   // R = Wm_h
        // ---- t_h = lrelu(agg_h @ Wg_h + bg_h)
        v4f acc[8];
#pragma unroll
        for (int t = 0; t < 8; ++t) acc[t] = (v4f){0.f, 0.f, 0.f, 0.f};
        __builtin_amdgcn_s_setprio(1);
#pragma unroll
        for (int kk = 0; kk < 4; ++kk) {
            short8 a = *reinterpret_cast<const short8*>(
                &agg[(size_t)amr * HF + h * FD + kk * 32 + kg]);
#pragma unroll
            for (int nt = 0; nt < 8; ++nt) {
                short8 b = *reinterpret_cast<const short8*>(&WL[nt * 16 + rA][kk * 32 + kg]);
                acc[nt] = __builtin_amdgcn_mfma_f32_16x16x32_bf16(a, b, acc[nt], 0, 0, 0);
            }
        }
        __builtin_amdgcn_s_setprio(0);
#pragma unroll
        for (int nt = 0; nt < 8; ++nt) {
            const int col = nt * 16 + rA;
            const float bv = biasg[h * FD + col];
#pragma unroll
            for (int i = 0; i < 4; ++i)
                tS[lr0 + i][col] = f2bf(lrelu(acc[nt][i] + bv, 0.01f));
        }
        COMMIT();               // WL = Wm_h (barrier covers Wg reads)
        PREFETCH((h < 3 ? WgT + (h + 1) * FD * FD : W1T), FD);
        // ---- hm += t_h @ Wm_h
        __builtin_amdgcn_s_setprio(1);
#pragma unroll
        for (int kk = 0; kk < 4; ++kk) {
            short8 a = *reinterpret_cast<const short8*>(&tS[wv * 16 + rA][kk * 32 + kg]);
#pragma unroll
            for (int nt = 0; nt < 8; ++nt) {
                short8 b = *reinterpret_cast<const short8*>(&WL[nt * 16 + rA][kk * 32 + kg]);
                hma[nt] = __builtin_amdgcn_mfma_f32_16x16x32_bf16(a, b, hma[nt], 0, 0, 0);
            }
        }
        __builtin_amdgcn_s_setprio(0);
    }

    // ---- hm finalize: + bm + x (fp32 kept in hma for exact residual; bf16 to tS)
#pragma unroll
    for (int nt = 0; nt < 8; ++nt) {
        const int col = nt * 16 + rA;
        const float bv = bm[col];
#pragma unroll
        for (int i = 0; i < 4; ++i) {
            const int r = min(mw + (l >> 4) * 4 + i, n - 1);
            float v = hma[nt][i] + bv + x[(size_t)r * FD + col];
            hma[nt][i] = v;
            tS[lr0 + i][col] = f2bf(v);
        }
    }
    COMMIT();                   // WL = W1 (barrier covers Wm_3 reads)
    PREFETCH(W2T, FD);
    // ---- FFN1: t2 = lrelu(hm @ W1 + b1)
    v4f acc[8];
#pragma unroll
    for (int t = 0; t < 8; ++t) acc[t] = (v4f){0.f, 0.f, 0.f, 0.f};
    __builtin_amdgcn_s_setprio(1);
#pragma unroll
    for (int kk = 0; kk < 4; ++kk) {
        short8 a = *reinterpret_cast<const short8*>(&tS[wv * 16 + rA][kk * 32 + kg]);
#pragma unroll
        for (int nt = 0; nt < 8; ++nt) {
            short8 b = *reinterpret_cast<const short8*>(&WL[nt * 16 + rA][kk * 32 + kg]);
            acc[nt] = __builtin_amdgcn_mfma_f32_16x16x32_bf16(a, b, acc[nt], 0, 0, 0);
        }
    }
    __builtin_amdgcn_s_setprio(0);
#pragma unroll
    for (int nt = 0; nt < 8; ++nt) {
        const int col = nt * 16 + rA;
        const float bv = b1[col];
#pragma unroll
        for (int i = 0; i < 4; ++i)
            tS[lr0 + i][col] = f2bf(lrelu(acc[nt][i] + bv, 0.01f));
    }
    COMMIT();                   // WL = W2 (barrier covers W1 reads)
    // ---- FFN2: out = t2 @ W2 + b2 + hm
#pragma unroll
    for (int t = 0; t < 8; ++t) acc[t] = (v4f){0.f, 0.f, 0.f, 0.f};
    __builtin_amdgcn_s_setprio(1);
#pragma unroll
    for (int kk = 0; kk < 4; ++kk) {
        short8 a = *reinterpret_cast<const short8*>(&tS[wv * 16 + rA][kk * 32 + kg]);
#pragma unroll
        for (int nt = 0; nt < 8; ++nt) {
            short8 b = *reinterpret_cast<const short8*>(&WL[nt * 16 + rA][kk * 32 + kg]);
            acc[nt] = __builtin_amdgcn_mfma_f32_16x16x32_bf16(a, b, acc[nt], 0, 0, 0);
        }
    }
    __builtin_amdgcn_s_setprio(0);
#pragma unroll
    for (int nt = 0; nt < 8; ++nt) {
        const int col = nt * 16 + rA;
        const float bv = b2[col];
#pragma unroll
        for (int i = 0; i < 4; ++i) {
            const int r = mw + (l >> 4) * 4 + i;
            if (r < n)
                out[(size_t)r * FD + col] = acc[nt][i] + bv + hma[nt][i];
        }
    }
}

extern "C" void kernel_launch(void* const* d_in, const int* in_sizes, int n_in,
                              void* d_out, int out_size, void* d_ws, size_t ws_size,
                              hipStream_t stream) {
    const float* x     = (const float*)d_in[0];
    const int*   ei    = (const int*)d_in[1];
    const float* Wg    = (const float*)d_in[2];
    const float* att_s = (const float*)d_in[3];
    const float* att_d = (const float*)d_in[4];
    const float* biasg = (const float*)d_in[5];
    const float* Wm    = (const float*)d_in[6];
    const float* bm    = (const float*)d_in[7];
    const float* W1    = (const float*)d_in[8];
    const float* b1    = (const float*)d_in[9];
    const float* W2    = (const float*)d_in[10];
    const float* b2    = (const float*)d_in[11];
    float* out = (float*)d_out;

    const int n = in_sizes[0] / FD;
    const int E = in_sizes[1] / 2;
    const int* esrc = ei;
    const int* edst = ei + E;

    char* w = (char*)d_ws;
    size_t o = 0;
    auto alloc = [&](size_t b) { void* p = w + o; o = (o + b + 255) & ~(size_t)255; return p; };
    unsigned short* x_b  = (unsigned short*)alloc((size_t)n * FD * 2);
    unsigned short* WgT  = (unsigned short*)alloc((size_t)FD * HF * 2);
    unsigned short* WmT  = (unsigned short*)alloc((size_t)HF * FD * 2);
    unsigned short* W1T  = (unsigned short*)alloc((size_t)FD * FD * 2);
    unsigned short* W2T  = (unsigned short*)alloc((size_t)FD * FD * 2);
    float*          U    = (float*)alloc(1024 * 4);
    unsigned short* aggb = (unsigned short*)alloc((size_t)n * HF * 2);
    float* a_s   = (float*)alloc((size_t)n * NH * 4);
    float* a_d   = (float*)alloc((size_t)n * NH * 4);
    int*   cnt   = (int*)alloc((size_t)n * 4);
    int*   offs  = (int*)alloc((size_t)(n + 1) * 4);
    int*   cur   = (int*)alloc((size_t)n * 4);
    int*   ssort = (int*)alloc((size_t)E * 4);
    float* asort = (float*)alloc((size_t)E * 16);
    int*   bsum  = (int*)alloc(256 * 4);
    int*   bpre  = (int*)alloc(256 * 4);

    hipMemsetAsync(cnt, 0, (size_t)n * 4, stream);

    const int nCast = (n * FD / 8 + 255) / 256;
    const int nT1 = (FD * HF / 4 + 255) / 256;
    const int nT3 = (FD * FD / 4 + 255) / 256;
    const int nU = 4;
    const int nCnt = (E + 255) / 256;
    k_prep<<<nCast + 2 * nT1 + 2 * nT3 + nU + nCnt, 256, 0, stream>>>(
        x, x_b, Wg, WgT, Wm, WmT, W1, W1T, W2, W2T, att_s, att_d, U, edst, cnt, n, E);

    k_alog<<<(n * 4 + 255) / 256, 256, 0, stream>>>(x, U, a_s, a_d, n);

    const int SB = (n + 4095) / 4096;
    k_scanA<<<SB, 1024, 0, stream>>>(cnt, bsum, n);
    k_scanB<<<1, 64, 0, stream>>>(bsum, bpre, SB);
    k_scanC<<<SB, 1024, 0, stream>>>(cnt, bpre, offs, cur, n);
    k_scatter<<<(E + 255) / 256, 256, 0, stream>>>(esrc, edst, a_s, a_d, cur, ssort,
                                                   (float4*)asort, E);
    k_aggr2<<<(n + 3) / 4, 256, 0, stream>>>(x_b, a_s, a_d, offs, ssort, asort, aggb, n);

    const int mb2 = (n + 127) / 128;
    k_tail<<<mb2, 512, 0, stream>>>(aggb, WgT, biasg, WmT, bm, x, W1T, b1, W2T, b2, out, n);
}

// Round 9
// 241.217 us; speedup vs baseline: 1.6186x; 1.1284x over previous
//
#include <hip/hip_runtime.h>

#define FD 128
#define NH 4
#define HF 512

typedef __attribute__((ext_vector_type(8))) short short8;
typedef __attribute__((ext_vector_type(4))) float v4f;

__device__ __forceinline__ float lrelu(float x, float s) { return x > 0.f ? x : s * x; }

__device__ __forceinline__ unsigned short f2bf(float f) {
    unsigned int u = __float_as_uint(f);
    u += 0x7FFFu + ((u >> 16) & 1u);          // RNE
    return (unsigned short)(u >> 16);
}
__device__ __forceinline__ unsigned int pack2(float a, float b) {
    return (unsigned)f2bf(a) | ((unsigned)f2bf(b) << 16);
}

// ---------------- fused prep: cast x->bf16, weight transpose-casts, u=Wg_h@att, degree count
__global__ __launch_bounds__(256) void k_prep(const float* __restrict__ x,
                                              unsigned short* __restrict__ xb,
                                              const float* __restrict__ Wg, unsigned short* __restrict__ WgT,
                                              const float* __restrict__ Wm, unsigned short* __restrict__ WmT,
                                              const float* __restrict__ W1, unsigned short* __restrict__ W1T,
                                              const float* __restrict__ W2, unsigned short* __restrict__ W2T,
                                              const float* __restrict__ att_s,
                                              const float* __restrict__ att_d,
                                              float* __restrict__ U,
                                              const int* __restrict__ dst, int* __restrict__ cnt,
                                              int n, int E) {
    const int t = threadIdx.x;
    int b = blockIdx.x;
    const int nCast = (n * FD / 8 + 255) / 256;
    const int nT1 = (FD * HF / 4 + 255) / 256;
    const int nT3 = (FD * FD / 4 + 255) / 256;
    const int nU = 4;
    if (b < nCast) {
        int i = b * 256 + t;
        if (i < n * FD / 8) {
            const float4* x4 = reinterpret_cast<const float4*>(x);
            float4 v0 = x4[i * 2], v1 = x4[i * 2 + 1];
            uint4 o;
            o.x = pack2(v0.x, v0.y); o.y = pack2(v0.z, v0.w);
            o.z = pack2(v1.x, v1.y); o.w = pack2(v1.z, v1.w);
            reinterpret_cast<uint4*>(xb)[i] = o;
        }
        return;
    }
    b -= nCast;
    if (b < nT1) {   // WgT[512][128] <- Wg[128][512]
        int i4 = (b * 256 + t) * 4;
        if (i4 < FD * HF) {
            int nn = i4 >> 7, k = i4 & 127;
            uint2 o;
            o.x = pack2(Wg[(size_t)k * HF + nn], Wg[(size_t)(k + 1) * HF + nn]);
            o.y = pack2(Wg[(size_t)(k + 2) * HF + nn], Wg[(size_t)(k + 3) * HF + nn]);
            *reinterpret_cast<uint2*>(&WgT[i4]) = o;
        }
        return;
    }
    b -= nT1;
    if (b < nT1) {   // WmT[128][512] <- Wm[512][128]
        int i4 = (b * 256 + t) * 4;
        if (i4 < HF * FD) {
            int nn = i4 >> 9, k = i4 & 511;
            uint2 o;
            o.x = pack2(Wm[(size_t)k * FD + nn], Wm[(size_t)(k + 1) * FD + nn]);
            o.y = pack2(Wm[(size_t)(k + 2) * FD + nn], Wm[(size_t)(k + 3) * FD + nn]);
            *reinterpret_cast<uint2*>(&WmT[i4]) = o;
        }
        return;
    }
    b -= nT1;
    if (b < nT3) {   // W1T[128][128]
        int i4 = (b * 256 + t) * 4;
        if (i4 < FD * FD) {
            int nn = i4 >> 7, k = i4 & 127;
            uint2 o;
            o.x = pack2(W1[(size_t)k * FD + nn], W1[(size_t)(k + 1) * FD + nn]);
            o.y = pack2(W1[(size_t)(k + 2) * FD + nn], W1[(size_t)(k + 3) * FD + nn]);
            *reinterpret_cast<uint2*>(&W1T[i4]) = o;
        }
        return;
    }
    b -= nT3;
    if (b < nT3) {   // W2T[128][128]
        int i4 = (b * 256 + t) * 4;
        if (i4 < FD * FD) {
            int nn = i4 >> 7, k = i4 & 127;
            uint2 o;
            o.x = pack2(W2[(size_t)k * FD + nn], W2[(size_t)(k + 1) * FD + nn]);
            o.y = pack2(W2[(size_t)(k + 2) * FD + nn], W2[(size_t)(k + 3) * FD + nn]);
            *reinterpret_cast<uint2*>(&W2T[i4]) = o;
        }
        return;
    }
    b -= nT3;
    if (b < nU) {    // U[0..511]=u_s[h][k], U[512..1023]=u_d[h][k]
        int idx = b * 256 + t;
        int type = idx >> 9, h = (idx >> 7) & 3, k = idx & 127;
        const float* att = type ? att_d : att_s;
        const float* wrow = &Wg[(size_t)k * HF + h * FD];
        const float* arow = &att[h * FD];
        float s = 0.f;
#pragma unroll 4
        for (int j = 0; j < FD; ++j) s += wrow[j] * arow[j];
        U[idx] = s;
        return;
    }
    b -= nU;
    {
        int i = b * 256 + t;
        if (i < E) atomicAdd(&cnt[dst[i]], 1);
    }
}

// ---------------- a_s[n,h] = x[n]·u_s[h], a_d[n,h] = x[n]·u_d[h]  (reads bf16 x_b)
__global__ __launch_bounds__(256) void k_alog(const unsigned short* __restrict__ xb,
                                              const float* __restrict__ U,
                                              float* __restrict__ a_s,
                                              float* __restrict__ a_d, int n) {
    int idx = blockIdx.x * 256 + threadIdx.x;
    int node = idx >> 2, h = idx & 3;
    if (node >= n) return;
    const uint4* xr = reinterpret_cast<const uint4*>(&xb[(size_t)node * FD]);
    const float* us = &U[h * FD];
    const float* ud = &U[512 + h * FD];
    float ps = 0.f, pd = 0.f;
#pragma unroll 4
    for (int j = 0; j < 16; ++j) {
        uint4 u = xr[j];
        const unsigned w[4] = {u.x, u.y, u.z, u.w};
#pragma unroll
        for (int q = 0; q < 4; ++q) {
            float f0 = __uint_as_float(w[q] << 16);
            float f1 = __uint_as_float(w[q] & 0xffff0000u);
            int c = j * 8 + q * 2;
            ps += f0 * us[c] + f1 * us[c + 1];
            pd += f0 * ud[c] + f1 * ud[c + 1];
        }
    }
    a_s[node * NH + h] = ps;
    a_d[node * NH + h] = pd;
}

// ---------------- multi-block exclusive scan (3 phases)
__global__ __launch_bounds__(1024) void k_scanA(const int* __restrict__ cnt,
                                                int* __restrict__ bsum, int n) {
    __shared__ int wtot[16];
    const int b = blockIdx.x, t = threadIdx.x;
    const int lane = t & 63, wid = t >> 6;
    const int idx = b * 4096 + t * 4;
    int s = 0;
    if (idx + 3 < n) {
        int4 v = *reinterpret_cast<const int4*>(&cnt[idx]);
        s = v.x + v.y + v.z + v.w;
    } else {
        for (int j = 0; j < 4; ++j) if (idx + j < n) s += cnt[idx + j];
    }
#pragma unroll
    for (int d = 1; d < 64; d <<= 1) s += __shfl_xor(s, d);
    if (lane == 0) wtot[wid] = s;
    __syncthreads();
    if (t == 0) {
        int tot = 0;
#pragma unroll
        for (int i = 0; i < 16; ++i) tot += wtot[i];
        bsum[b] = tot;
    }
}

__global__ void k_scanB(const int* __restrict__ bsum, int* __restrict__ bpre, int nb) {
    const int l = threadIdx.x;
    int v = (l < nb) ? bsum[l] : 0;
    int incl = v;
#pragma unroll
    for (int d = 1; d < 64; d <<= 1) {
        int o = __shfl_up(incl, d);
        if (l >= d) incl += o;
    }
    if (l < nb) bpre[l] = incl - v;
}

__global__ __launch_bounds__(1024) void k_scanC(const int* __restrict__ cnt,
                                                const int* __restrict__ bpre,
                                                int* __restrict__ off,
                                                int* __restrict__ cur, int n) {
    __shared__ int wtot[16];
    const int b = blockIdx.x, t = threadIdx.x;
    const int lane = t & 63, wid = t >> 6;
    const int idx = b * 4096 + t * 4;
    int4 v = make_int4(0, 0, 0, 0);
    if (idx + 3 < n) v = *reinterpret_cast<const int4*>(&cnt[idx]);
    else {
        if (idx < n) v.x = cnt[idx];
        if (idx + 1 < n) v.y = cnt[idx + 1];
        if (idx + 2 < n) v.z = cnt[idx + 2];
        if (idx + 3 < n) v.w = cnt[idx + 3];
    }
    const int p1 = v.x, p2 = p1 + v.y, p3 = p2 + v.z, ts = p3 + v.w;
    int incl = ts;
#pragma unroll
    for (int d = 1; d < 64; d <<= 1) {
        int o = __shfl_up(incl, d);
        if (lane >= d) incl += o;
    }
    if (lane == 63) wtot[wid] = incl;
    __syncthreads();
    int wbase = 0;
#pragma unroll
    for (int i = 0; i < 16; ++i) if (i < wid) wbase += wtot[i];
    const int base = bpre[b] + wbase + (incl - ts);
    if (idx < n)     { cur[idx] = base;          off[idx + 1] = base + p1; }
    if (idx + 1 < n) { cur[idx + 1] = base + p1; off[idx + 2] = base + p2; }
    if (idx + 2 < n) { cur[idx + 2] = base + p2; off[idx + 3] = base + p3; }
    if (idx + 3 < n) { cur[idx + 3] = base + p3; off[idx + 4] = base + ts; }
    if (b == 0 && t == 0) off[0] = 0;
}

// ---------------- scatter edges into CSR slots; store EXP'd leaky(0.2) weights
__global__ __launch_bounds__(256) void k_scatter(const int* __restrict__ es,
                                                 const int* __restrict__ ed,
                                                 const float* __restrict__ a_s,
                                                 const float* __restrict__ a_d,
                                                 int* __restrict__ cur,
                                                 int* __restrict__ ssort,
                                                 float4* __restrict__ asort, int e) {
    int i = blockIdx.x * 256 + threadIdx.x;
    if (i >= e) return;
    int s = es[i], d = ed[i];
    const float4 as = *reinterpret_cast<const float4*>(&a_s[(size_t)s * NH]);
    const float4 ad = *reinterpret_cast<const float4*>(&a_d[(size_t)d * NH]);
    float4 al;
    al.x = __expf(lrelu(as.x + ad.x, 0.2f));
    al.y = __expf(lrelu(as.y + ad.y, 0.2f));
    al.z = __expf(lrelu(as.z + ad.z, 0.2f));
    al.w = __expf(lrelu(as.w + ad.w, 0.2f));
    int pos = atomicAdd(&cur[d], 1);
    ssort[pos] = s;
    asort[pos] = al;
}

// ---------------- per-node (one wave) aggregation in x-space -> agg bf16 [n][h*128+k]
// Edge (src, w4) batches staged via per-wave LDS broadcast (double-buffered):
// lanes 0-15 coalesce-load 16 edges, all lanes ds_read-broadcast per edge.
// No shfl, no exp in the loop; every lane redundantly accumulates all 4 denominators.
__global__ __launch_bounds__(256) void k_aggr2(const unsigned short* __restrict__ xb,
                                               const float* __restrict__ a_s,
                                               const float* __restrict__ a_d,
                                               const int* __restrict__ off,
                                               const int* __restrict__ ssort,
                                               const float4* __restrict__ awx,
                                               unsigned short* __restrict__ agg, int n) {
    __shared__ float4 wst[4][2][16];
    __shared__ int    sst[4][2][16];
    const int wv = threadIdx.x >> 6, l = threadIdx.x & 63;
    const int node = blockIdx.x * 4 + wv;
    if (node >= n) return;
    const int e16 = l & 15;
    const bool ld = l < 16;
    const int o0 = off[node], deg = off[node + 1] - o0;

    float wS[4];
#pragma unroll
    for (int h = 0; h < 4; ++h)
        wS[h] = __expf(lrelu(a_s[node * NH + h] + a_d[node * NH + h], 0.2f));

    float ax[4], ay[4];
    {
        unsigned ux = *reinterpret_cast<const unsigned*>(&xb[(size_t)node * FD + 2 * l]);
        float f0 = __uint_as_float(ux << 16);
        float f1 = __uint_as_float(ux & 0xffff0000u);
#pragma unroll
        for (int h = 0; h < 4; ++h) { ax[h] = f0 * wS[h]; ay[h] = f1 * wS[h]; }
    }
    float den[4] = {0.f, 0.f, 0.f, 0.f};

    const int* sso = ssort + o0;
    const float4* aw = awx + o0;
    const int nbat = deg >> 4, rem = deg & 15;

    float4 rw; int rs = 0;
    rw.x = rw.y = rw.z = rw.w = 0.f;
    if (ld && e16 < deg) { rw = aw[e16]; rs = sso[e16]; }

    for (int b = 0; b < nbat; ++b) {
        const int cb = b & 1;
        if (ld) { wst[wv][cb][e16] = rw; sst[wv][cb][e16] = rs; }
        {
            int nx = (b + 1) * 16 + e16;
            if (ld && nx < deg) { rw = aw[nx]; rs = sso[nx]; }
        }
#pragma unroll
        for (int e = 0; e < 16; ++e) {
            float4 w4 = wst[wv][cb][e];
            int s = sst[wv][cb][e];
            unsigned u = *reinterpret_cast<const unsigned*>(&xb[(size_t)s * FD + 2 * l]);
            float f0 = __uint_as_float(u << 16);
            float f1 = __uint_as_float(u & 0xffff0000u);
            ax[0] += f0 * w4.x; ay[0] += f1 * w4.x;
            ax[1] += f0 * w4.y; ay[1] += f1 * w4.y;
            ax[2] += f0 * w4.z; ay[2] += f1 * w4.z;
            ax[3] += f0 * w4.w; ay[3] += f1 * w4.w;
            den[0] += w4.x; den[1] += w4.y; den[2] += w4.z; den[3] += w4.w;
        }
    }
    if (rem) {
        const int cb = nbat & 1;
        if (ld && e16 < rem) { wst[wv][cb][e16] = rw; sst[wv][cb][e16] = rs; }
        for (int e = 0; e < rem; ++e) {
            float4 w4 = wst[wv][cb][e];
            int s = sst[wv][cb][e];
            unsigned u = *reinterpret_cast<const unsigned*>(&xb[(size_t)s * FD + 2 * l]);
            float f0 = __uint_as_float(u << 16);
            float f1 = __uint_as_float(u & 0xffff0000u);
            ax[0] += f0 * w4.x; ay[0] += f1 * w4.x;
            ax[1] += f0 * w4.y; ay[1] += f1 * w4.y;
            ax[2] += f0 * w4.z; ay[2] += f1 * w4.z;
            ax[3] += f0 * w4.w; ay[3] += f1 * w4.w;
            den[0] += w4.x; den[1] += w4.y; den[2] += w4.z; den[3] += w4.w;
        }
    }
#pragma unroll
    for (int h = 0; h < 4; ++h) {
        float inv = 1.f / (den[h] + wS[h]);
        unsigned o = pack2(ax[h] * inv, ay[h] * inv);
        *reinterpret_cast<unsigned*>(&agg[(size_t)node * HF + h * FD + 2 * l]) = o;
    }
}

// ---------------- fused tail, M=128 / 512 threads / prefetch-pipelined weight staging.
#define PREFETCH(BP, STRIDE) do {                                              \
    _Pragma("unroll")                                                          \
    for (int rnd = 0; rnd < 4; ++rnd) {                                        \
        int r_ = rnd * 32 + sr;                                                \
        R[rnd] = *reinterpret_cast<const short8*>(&(BP)[(size_t)r_ * (STRIDE) + sc]); \
    } } while (0)

#define COMMIT() do {                                                          \
    __syncthreads();                                                           \
    _Pragma("unroll")                                                          \
    for (int rnd = 0; rnd < 4; ++rnd) {                                        \
        int r_ = rnd * 32 + sr;                                                \
        *reinterpret_cast<short8*>(&WL[r_][sc]) = R[rnd];                      \
    }                                                                          \
    __syncthreads(); } while (0)

__global__ __launch_bounds__(512, 4) void k_tail(const unsigned short* __restrict__ agg,
                                                 const unsigned short* __restrict__ WgT,
                                                 const float* __restrict__ biasg,
                                                 const unsigned short* __restrict__ WmT,
                                                 const float* __restrict__ bm,
                                                 const float* __restrict__ x,
                                                 const unsigned short* __restrict__ W1T,
                                                 const float* __restrict__ b1,
                                                 const unsigned short* __restrict__ W2T,
                                                 const float* __restrict__ b2,
                                                 float* __restrict__ out, int n) {
    __shared__ unsigned short WL[128][132];   // 33.8 KB weight tile
    __shared__ unsigned short tS[128][132];   // 33.8 KB bridge
    const int tid = threadIdx.x;
    const int m0 = blockIdx.x * 128;
    const int wv = tid >> 6, l = tid & 63;
    const int rA = l & 15;
    const int kg = (l >> 4) * 8;
    const int mw = m0 + wv * 16;
    const int amr = min(mw + rA, n - 1);
    const int lr0 = wv * 16 + (l >> 4) * 4;
    const int sr = tid >> 4, sc = (tid & 15) * 8;

    short8 R[4];
    v4f hma[8];
#pragma unroll
    for (int t = 0; t < 8; ++t) hma[t] = (v4f){0.f, 0.f, 0.f, 0.f};

    PREFETCH(WgT, FD);          // R = Wg_0

#pragma unroll
    for (int h = 0; h < 4; ++h) {
        COMMIT();               // WL = Wg_h
        PREFETCH(WmT + h * FD, HF);   // R = Wm_h
        v4f acc[8];
#pragma unroll
        for (int t = 0; t < 8; ++t) acc[t] = (v4f){0.f, 0.f, 0.f, 0.f};
        __builtin_amdgcn_s_setprio(1);
#pragma unroll
        for (int kk = 0; kk < 4; ++kk) {
            short8 a = *reinterpret_cast<const short8*>(
                &agg[(size_t)amr * HF + h * FD + kk * 32 + kg]);
#pragma unroll
            for (int nt = 0; nt < 8; ++nt) {
                short8 b = *reinterpret_cast<const short8*>(&WL[nt * 16 + rA][kk * 32 + kg]);
                acc[nt] = __builtin_amdgcn_mfma_f32_16x16x32_bf16(a, b, acc[nt], 0, 0, 0);
            }
        }
        __builtin_amdgcn_s_setprio(0);
#pragma unroll
        for (int nt = 0; nt < 8; ++nt) {
            const int col = nt * 16 + rA;
            const float bv = biasg[h * FD + col];
#pragma unroll
            for (int i = 0; i < 4; ++i)
                tS[lr0 + i][col] = f2bf(lrelu(acc[nt][i] + bv, 0.01f));
        }
        COMMIT();               // WL = Wm_h (barrier covers Wg reads)
        PREFETCH((h < 3 ? WgT + (h + 1) * FD * FD : W1T), FD);
        __builtin_amdgcn_s_setprio(1);
#pragma unroll
        for (int kk = 0; kk < 4; ++kk) {
            short8 a = *reinterpret_cast<const short8*>(&tS[wv * 16 + rA][kk * 32 + kg]);
#pragma unroll
            for (int nt = 0; nt < 8; ++nt) {
                short8 b = *reinterpret_cast<const short8*>(&WL[nt * 16 + rA][kk * 32 + kg]);
                hma[nt] = __builtin_amdgcn_mfma_f32_16x16x32_bf16(a, b, hma[nt], 0, 0, 0);
            }
        }
        __builtin_amdgcn_s_setprio(0);
    }

#pragma unroll
    for (int nt = 0; nt < 8; ++nt) {
        const int col = nt * 16 + rA;
        const float bv = bm[col];
#pragma unroll
        for (int i = 0; i < 4; ++i) {
            const int r = min(mw + (l >> 4) * 4 + i, n - 1);
            float v = hma[nt][i] + bv + x[(size_t)r * FD + col];
            hma[nt][i] = v;
            tS[lr0 + i][col] = f2bf(v);
        }
    }
    COMMIT();                   // WL = W1 (barrier covers Wm_3 reads)
    PREFETCH(W2T, FD);
    v4f acc[8];
#pragma unroll
    for (int t = 0; t < 8; ++t) acc[t] = (v4f){0.f, 0.f, 0.f, 0.f};
    __builtin_amdgcn_s_setprio(1);
#pragma unroll
    for (int kk = 0; kk < 4; ++kk) {
        short8 a = *reinterpret_cast<const short8*>(&tS[wv * 16 + rA][kk * 32 + kg]);
#pragma unroll
        for (int nt = 0; nt < 8; ++nt) {
            short8 b = *reinterpret_cast<const short8*>(&WL[nt * 16 + rA][kk * 32 + kg]);
            acc[nt] = __builtin_amdgcn_mfma_f32_16x16x32_bf16(a, b, acc[nt], 0, 0, 0);
        }
    }
    __builtin_amdgcn_s_setprio(0);
#pragma unroll
    for (int nt = 0; nt < 8; ++nt) {
        const int col = nt * 16 + rA;
        const float bv = b1[col];
#pragma unroll
        for (int i = 0; i < 4; ++i)
            tS[lr0 + i][col] = f2bf(lrelu(acc[nt][i] + bv, 0.01f));
    }
    COMMIT();                   // WL = W2 (barrier covers W1 reads)
#pragma unroll
    for (int t = 0; t < 8; ++t) acc[t] = (v4f){0.f, 0.f, 0.f, 0.f};
    __builtin_amdgcn_s_setprio(1);
#pragma unroll
    for (int kk = 0; kk < 4; ++kk) {
        short8 a = *reinterpret_cast<const short8*>(&tS[wv * 16 + rA][kk * 32 + kg]);
#pragma unroll
        for (int nt = 0; nt < 8; ++nt) {
            short8 b = *reinterpret_cast<const short8*>(&WL[nt * 16 + rA][kk * 32 + kg]);
            acc[nt] = __builtin_amdgcn_mfma_f32_16x16x32_bf16(a, b, acc[nt], 0, 0, 0);
        }
    }
    __builtin_amdgcn_s_setprio(0);
#pragma unroll
    for (int nt = 0; nt < 8; ++nt) {
        const int col = nt * 16 + rA;
        const float bv = b2[col];
#pragma unroll
        for (int i = 0; i < 4; ++i) {
            const int r = mw + (l >> 4) * 4 + i;
            if (r < n)
                out[(size_t)r * FD + col] = acc[nt][i] + bv + hma[nt][i];
        }
    }
}

extern "C" void kernel_launch(void* const* d_in, const int* in_sizes, int n_in,
                              void* d_out, int out_size, void* d_ws, size_t ws_size,
                              hipStream_t stream) {
    const float* x     = (const float*)d_in[0];
    const int*   ei    = (const int*)d_in[1];
    const float* Wg    = (const float*)d_in[2];
    const float* att_s = (const float*)d_in[3];
    const float* att_d = (const float*)d_in[4];
    const float* biasg = (const float*)d_in[5];
    const float* Wm    = (const float*)d_in[6];
    const float* bm    = (const float*)d_in[7];
    const float* W1    = (const float*)d_in[8];
    const float* b1    = (const float*)d_in[9];
    const float* W2    = (const float*)d_in[10];
    const float* b2    = (const float*)d_in[11];
    float* out = (float*)d_out;

    const int n = in_sizes[0] / FD;
    const int E = in_sizes[1] / 2;
    const int* esrc = ei;
    const int* edst = ei + E;

    char* w = (char*)d_ws;
    size_t o = 0;
    auto alloc = [&](size_t b) { void* p = w + o; o = (o + b + 255) & ~(size_t)255; return p; };
    unsigned short* x_b  = (unsigned short*)alloc((size_t)n * FD * 2);
    unsigned short* WgT  = (unsigned short*)alloc((size_t)FD * HF * 2);
    unsigned short* WmT  = (unsigned short*)alloc((size_t)HF * FD * 2);
    unsigned short* W1T  = (unsigned short*)alloc((size_t)FD * FD * 2);
    unsigned short* W2T  = (unsigned short*)alloc((size_t)FD * FD * 2);
    float*          U    = (float*)alloc(1024 * 4);
    unsigned short* aggb = (unsigned short*)alloc((size_t)n * HF * 2);
    float* a_s   = (float*)alloc((size_t)n * NH * 4);
    float* a_d   = (float*)alloc((size_t)n * NH * 4);
    int*   cnt   = (int*)alloc((size_t)n * 4);
    int*   offs  = (int*)alloc((size_t)(n + 1) * 4);
    int*   cur   = (int*)alloc((size_t)n * 4);
    int*   ssort = (int*)alloc((size_t)E * 4);
    float* asort = (float*)alloc((size_t)E * 16);
    int*   bsum  = (int*)alloc(256 * 4);
    int*   bpre  = (int*)alloc(256 * 4);

    hipMemsetAsync(cnt, 0, (size_t)n * 4, stream);

    const int nCast = (n * FD / 8 + 255) / 256;
    const int nT1 = (FD * HF / 4 + 255) / 256;
    const int nT3 = (FD * FD / 4 + 255) / 256;
    const int nU = 4;
    const int nCnt = (E + 255) / 256;
    k_prep<<<nCast + 2 * nT1 + 2 * nT3 + nU + nCnt, 256, 0, stream>>>(
        x, x_b, Wg, WgT, Wm, WmT, W1, W1T, W2, W2T, att_s, att_d, U, edst, cnt, n, E);

    k_alog<<<(n * 4 + 255) / 256, 256, 0, stream>>>(x_b, U, a_s, a_d, n);

    const int SB = (n + 4095) / 4096;
    k_scanA<<<SB, 1024, 0, stream>>>(cnt, bsum, n);
    k_scanB<<<1, 64, 0, stream>>>(bsum, bpre, SB);
    k_scanC<<<SB, 1024, 0, stream>>>(cnt, bpre, offs, cur, n);
    k_scatter<<<(E + 255) / 256, 256, 0, stream>>>(esrc, edst, a_s, a_d, cur, ssort,
                                                   (float4*)asort, E);
    k_aggr2<<<(n + 3) / 4, 256, 0, stream>>>(x_b, a_s, a_d, offs, ssort,
                                             (const float4*)asort, aggb, n);

    const int mb2 = (n + 127) / 128;
    k_tail<<<mb2, 512, 0, stream>>>(aggb, WgT, biasg, WmT, bm, x, W1T, b1, W2T, b2, out, n);
}